// Round 2
// baseline (949.053 us; speedup 1.0000x reference)
//
#include <hip/hip_runtime.h>
#include <math.h>

#define DEV static __device__ __forceinline__

typedef unsigned int  u32;
typedef unsigned short u16;

static constexpr int B_ = 16;
static constexpr int C_ = 512;
static constexpr int H_ = 48;
static constexpr int W_ = 48;
static constexpr int L_ = 2304;      // H*W
static constexpr int M_ = B_ * L_;   // 36864
static constexpr int SEG_ = 18;      // scan segments
static constexpr int TSEG_ = 128;    // 18*128 = 2304

DEV float silu_(float v) { return v / (1.f + __expf(-v)); }
DEV float bflo(u32 p) { return __uint_as_float(p << 16); }
DEV float bfhi(u32 p) { return __uint_as_float(p & 0xffff0000u); }
DEV float bf2f(u16 v) { return __uint_as_float(((u32)v) << 16); }
DEV u16 f2bf(float f) { u32 u = __float_as_uint(f); u32 r = u + 0x7fffu + ((u >> 16) & 1u); return (u16)(r >> 16); }

// sequence position l (direction k) -> spatial index sp = h*W + w
DEV int seq_to_sp(int k, int l) {
  int ll = (k & 1) ? (L_ - 1 - l) : l;
  if (k >= 2) return (ll % H_) * W_ + (ll / H_);   // l = w*H + h
  return ll;
}

// ---------------- K1: layernorm over C of x transposed to (B,L,C), bf16 out ----------------
__global__ __launch_bounds__(256) void k_ln_in(const float* __restrict__ x,
    const float* __restrict__ w, const float* __restrict__ bia, u16* __restrict__ xs) {
  __shared__ float tile[16 * 513];
  __shared__ float smean[16], srstd[16];
  const int b = blockIdx.y;
  const int l0 = blockIdx.x * 16;
  const int tid = threadIdx.x;
  const float* xb = x + (size_t)b * C_ * L_;
  for (int idx = tid; idx < C_ * 16; idx += 256) {
    int c = idx >> 4, lt = idx & 15;
    tile[lt * 513 + c] = xb[(size_t)c * L_ + l0 + lt];
  }
  __syncthreads();
  {
    const int j = tid & 15, g = tid >> 4;
    float s1 = 0.f, s2 = 0.f;
    #pragma unroll
    for (int i = 0; i < 32; ++i) {
      float v = tile[g * 513 + j + i * 16];
      s1 += v; s2 += v * v;
    }
    #pragma unroll
    for (int o = 8; o; o >>= 1) { s1 += __shfl_xor(s1, o, 16); s2 += __shfl_xor(s2, o, 16); }
    if (j == 0) {
      float mean = s1 * (1.f / C_);
      float var = s2 * (1.f / C_) - mean * mean;
      smean[g] = mean;
      srstd[g] = rsqrtf(var + 1e-5f);
    }
  }
  __syncthreads();
  for (int idx = tid; idx < 16 * C_; idx += 256) {
    int lt = idx >> 9, c = idx & 511;
    float v = (tile[lt * 513 + c] - smean[lt]) * srstd[lt] * w[c] + bia[c];
    xs[((size_t)b * L_ + l0 + lt) * C_ + c] = f2bf(v);
  }
}

// ---------------- K2: column means for SE (deterministic two-stage) ----------------
__global__ __launch_bounds__(256) void k_colsum_part(const u16* __restrict__ xs, float* __restrict__ zpart) {
  const int c = blockIdx.x * 256 + threadIdx.x;   // grid.x = 2
  const int b = blockIdx.y;
  const int s = blockIdx.z;                        // 18 segments of 128 rows
  float acc = 0.f;
  const u16* p = xs + ((size_t)b * L_ + s * 128) * C_ + c;
  for (int l = 0; l < 128; ++l) acc += bf2f(p[(size_t)l * C_]);
  zpart[((size_t)b * 18 + s) * C_ + c] = acc;
}

__global__ __launch_bounds__(256) void k_colsum_fin(const float* __restrict__ zpart, float* __restrict__ z) {
  const int c = blockIdx.x * 256 + threadIdx.x;
  const int b = blockIdx.y;
  float acc = 0.f;
  for (int s = 0; s < 18; ++s) acc += zpart[((size_t)b * 18 + s) * C_ + c];
  z[b * C_ + c] = acc * (1.f / L_);
}

// ---------------- K3: SE MLP ----------------
__global__ __launch_bounds__(256) void k_se(const float* __restrict__ z,
    const float* __restrict__ fc1w, const float* __restrict__ fc1b,
    const float* __restrict__ fc2w, const float* __restrict__ fc2b, float* __restrict__ se) {
  __shared__ float zs[512];
  __shared__ float hs[32];
  const int b = blockIdx.x, tid = threadIdx.x;
  zs[tid] = z[b * C_ + tid];
  zs[tid + 256] = z[b * C_ + tid + 256];
  __syncthreads();
  if (tid < 32) {
    float a = fc1b[tid];
    for (int c = 0; c < 512; ++c) a += zs[c] * fc1w[c * 32 + tid];
    hs[tid] = fmaxf(a, 0.f);
  }
  __syncthreads();
  for (int c = tid; c < 512; c += 256) {
    float a = fc2b[c];
    #pragma unroll
    for (int r = 0; r < 32; ++r) a += hs[r] * fc2w[r * 512 + c];
    se[b * C_ + c] = 1.f / (1.f + __expf(-a));
  }
}

// ---------------- K4: xz GEMM (per k): xs[:, k*128:+128] @ Win[k] (128 x 256) ----------------
__global__ __launch_bounds__(256) void k_gemm_xz(const u16* __restrict__ xs,
    const float* __restrict__ Win, u16* __restrict__ xin, u16* __restrict__ zbuf) {
  const int k = blockIdx.z;
  const int m0 = blockIdx.y * 64;
  const int n0 = blockIdx.x * 64;
  const u16* A = xs + k * 128;                   // lda = 512
  const float* Bw = Win + (size_t)k * 128 * 256; // ldb = 256
  __shared__ float As[16][68];
  __shared__ float Bs[16][68];
  const int tid = threadIdx.x;
  const int tx = tid & 15, ty = tid >> 4;
  float acc[4][4] = {};
  for (int kk0 = 0; kk0 < 128; kk0 += 16) {
    {
      int r = tid >> 2, c4 = tid & 3;
      uint2 v = *(const uint2*)(A + (size_t)(m0 + r) * 512 + kk0 + c4 * 4);
      As[c4 * 4 + 0][r] = bflo(v.x); As[c4 * 4 + 1][r] = bfhi(v.x);
      As[c4 * 4 + 2][r] = bflo(v.y); As[c4 * 4 + 3][r] = bfhi(v.y);
    }
    {
      int r = tid >> 4, c4 = tid & 15;
      *(float4*)&Bs[r][c4 * 4] = *(const float4*)(Bw + (size_t)(kk0 + r) * 256 + n0 + c4 * 4);
    }
    __syncthreads();
    #pragma unroll
    for (int kk = 0; kk < 16; ++kk) {
      float a[4], b[4];
      *(float4*)a = *(const float4*)&As[kk][ty * 4];
      #pragma unroll
      for (int j = 0; j < 4; ++j) b[j] = Bs[kk][j * 16 + tx];
      #pragma unroll
      for (int i = 0; i < 4; ++i)
        #pragma unroll
        for (int j = 0; j < 4; ++j) acc[i][j] += a[i] * b[j];
    }
    __syncthreads();
  }
  #pragma unroll
  for (int i = 0; i < 4; ++i) {
    int m = m0 + ty * 4 + i;
    size_t o = ((size_t)k * M_ + m) * 128;
    #pragma unroll
    for (int j = 0; j < 4; ++j) {
      int n = n0 + j * 16 + tx;
      u16 v = f2bf(acc[i][j]);
      if (n < 128) xin[o + n] = v;
      else zbuf[o + n - 128] = v;
    }
  }
}

// ---------------- K5: depthwise 3x3 conv + bias + silu (channel-last) ----------------
__global__ __launch_bounds__(256) void k_dwconv(const u16* __restrict__ xin,
    const float* __restrict__ cw, const float* __restrict__ cb, u16* __restrict__ xc) {
  const int kb = blockIdx.y;
  const int k = kb >> 4;
  const int tid = threadIdx.x;
  const int dc = tid & 127, si = tid >> 7;
  const int sp = blockIdx.x * 2 + si;
  const int h = sp / W_, w = sp % W_;
  const float* wp = cw + ((size_t)k * 128 + dc) * 9;
  float tap[9];
  #pragma unroll
  for (int t = 0; t < 9; ++t) tap[t] = wp[t];
  float acc = cb[k * 128 + dc];
  const u16* base = xin + (size_t)kb * L_ * 128 + dc;
  #pragma unroll
  for (int dy = -1; dy <= 1; ++dy) {
    int hh = h + dy;
    if (hh < 0 || hh >= H_) continue;
    #pragma unroll
    for (int dx = -1; dx <= 1; ++dx) {
      int ww = w + dx;
      if (ww < 0 || ww >= W_) continue;
      acc += tap[(dy + 1) * 3 + dx + 1] * bf2f(base[(size_t)(hh * W_ + ww) * 128]);
    }
  }
  xc[((size_t)kb * L_ + sp) * 128 + dc] = f2bf(silu_(acc));
}

// ---------------- K6: x_dbl = Wx[k] @ u   (stored per-sp, stride 16, fp32) ----------------
__global__ __launch_bounds__(256) void k_xdbl(const u16* __restrict__ xc,
    const float* __restrict__ Wx, float* __restrict__ xdbl) {
  __shared__ float wx[10 * 128];
  const int kb = blockIdx.y;
  const int k = kb >> 4;
  const int sp = blockIdx.x * 256 + threadIdx.x;   // grid.x = 9
  for (int i = threadIdx.x; i < 1280; i += 256) wx[i] = Wx[(size_t)k * 1280 + i];
  __syncthreads();
  float acc[10] = {};
  const u16* up = xc + ((size_t)kb * L_ + sp) * 128;
  for (int q = 0; q < 16; ++q) {
    uint4 v = *(const uint4*)(up + q * 8);
    float e[8] = {bflo(v.x), bfhi(v.x), bflo(v.y), bfhi(v.y),
                  bflo(v.z), bfhi(v.z), bflo(v.w), bfhi(v.w)};
    #pragma unroll
    for (int r = 0; r < 10; ++r) {
      const float* wr = &wx[r * 128 + q * 8];
      #pragma unroll
      for (int j = 0; j < 8; ++j) acc[r] += wr[j] * e[j];
    }
  }
  float* o = xdbl + ((size_t)kb * L_ + sp) * 16;
  #pragma unroll
  for (int r = 0; r < 10; ++r) o[r] = acc[r];
}

// ---------------- scan element: recompute delta/dA/dBu ----------------
DEV void scan_elem(const float* __restrict__ xr, const float wdt[8], float bias, float Aa,
                   float u, float& dA, float& dBu, float& Cm) {
  float4 q0 = *(const float4*)(xr);
  float4 q1 = *(const float4*)(xr + 4);
  float4 q2 = *(const float4*)(xr + 8);
  float dt = bias + wdt[0] * q0.x + wdt[1] * q0.y + wdt[2] * q0.z + wdt[3] * q0.w
                  + wdt[4] * q1.x + wdt[5] * q1.y + wdt[6] * q1.z + wdt[7] * q1.w;
  float delta = (dt > 20.f) ? dt : log1pf(__expf(dt));
  dA = __expf(delta * Aa);
  dBu = delta * u * q2.x;   // * Bm
  Cm = q2.y;
}

// ---------------- K7: scan pass A (per-segment aggregates) ----------------
__global__ __launch_bounds__(128) void k_scan_passA(const u16* __restrict__ xc,
    const float* __restrict__ xdbl, const float* __restrict__ Wdt, const float* __restrict__ dtb,
    const float* __restrict__ Alog, float* __restrict__ segA, float* __restrict__ segB) {
  const int kb = blockIdx.y;
  const int k = kb >> 4;
  const int s = blockIdx.x;
  const int dc = threadIdx.x;
  float wdt[8];
  #pragma unroll
  for (int r = 0; r < 8; ++r) wdt[r] = Wdt[((size_t)k * 128 + dc) * 8 + r];
  const float bias = dtb[k * 128 + dc];
  const float Aa = -__expf(Alog[k * 128 + dc]);
  float a = 1.f, bacc = 0.f;
  #pragma unroll 4
  for (int i = 0; i < TSEG_; ++i) {
    int l = s * TSEG_ + i;
    int sp = seq_to_sp(k, l);
    const float* xr = xdbl + ((size_t)kb * L_ + sp) * 16;
    float u = bf2f(xc[((size_t)kb * L_ + sp) * 128 + dc]);
    float dA, dBu, Cm;
    scan_elem(xr, wdt, bias, Aa, u, dA, dBu, Cm);
    a *= dA;
    bacc = dA * bacc + dBu;
  }
  segA[((size_t)kb * SEG_ + s) * 128 + dc] = a;
  segB[((size_t)kb * SEG_ + s) * 128 + dc] = bacc;
}

// ---------------- K8: scan pass B (serial across 18 segments) ----------------
__global__ __launch_bounds__(128) void k_scan_passB(const float* __restrict__ segA,
    const float* __restrict__ segB, float* __restrict__ hpre) {
  const int kb = blockIdx.x;
  const int dc = threadIdx.x;
  float h = 0.f;
  for (int s = 0; s < SEG_; ++s) {
    size_t o = ((size_t)kb * SEG_ + s) * 128 + dc;
    hpre[o] = h;
    h = segA[o] * h + segB[o];
  }
}

// ---------------- K9: scan pass C (apply, produce y in spatial layout) ----------------
__global__ __launch_bounds__(128) void k_scan_passC(const u16* __restrict__ xc,
    const float* __restrict__ xdbl, const float* __restrict__ Wdt, const float* __restrict__ dtb,
    const float* __restrict__ Alog, const float* __restrict__ Dp, const float* __restrict__ hpre,
    u16* __restrict__ y) {
  const int kb = blockIdx.y;
  const int k = kb >> 4;
  const int s = blockIdx.x;
  const int dc = threadIdx.x;
  float wdt[8];
  #pragma unroll
  for (int r = 0; r < 8; ++r) wdt[r] = Wdt[((size_t)k * 128 + dc) * 8 + r];
  const float bias = dtb[k * 128 + dc];
  const float Aa = -__expf(Alog[k * 128 + dc]);
  const float Dv = Dp[k * 128 + dc];
  float h = hpre[((size_t)kb * SEG_ + s) * 128 + dc];
  #pragma unroll 4
  for (int i = 0; i < TSEG_; ++i) {
    int l = s * TSEG_ + i;
    int sp = seq_to_sp(k, l);
    const float* xr = xdbl + ((size_t)kb * L_ + sp) * 16;
    float u = bf2f(xc[((size_t)kb * L_ + sp) * 128 + dc]);
    float dA, dBu, Cm;
    scan_elem(xr, wdt, bias, Aa, u, dA, dBu, Cm);
    h = dA * h + dBu;
    y[((size_t)kb * L_ + sp) * 128 + dc] = f2bf(h * Cm + Dv * u);
  }
}

// ---------------- K10: LN over d (onorm) + silu(z) gate ----------------
__global__ __launch_bounds__(256) void k_gate_ln(const u16* __restrict__ y,
    const u16* __restrict__ zbuf, const float* __restrict__ ow, const float* __restrict__ ob,
    u16* __restrict__ t) {
  const int row = blockIdx.x * 4 + (threadIdx.x >> 6);   // (kb*L + sp)
  const int lane = threadIdx.x & 63;
  const int kb = row / L_;
  const int k = kb >> 4;
  const u16* yr = y + (size_t)row * 128;
  float v0 = bf2f(yr[lane]), v1 = bf2f(yr[lane + 64]);
  float s1 = v0 + v1, s2 = v0 * v0 + v1 * v1;
  #pragma unroll
  for (int o = 32; o; o >>= 1) { s1 += __shfl_xor(s1, o, 64); s2 += __shfl_xor(s2, o, 64); }
  float mean = s1 * (1.f / 128.f);
  float rstd = rsqrtf(s2 * (1.f / 128.f) - mean * mean + 1e-5f);
  const u16* zr = zbuf + (size_t)row * 128;
  float g0 = silu_(bf2f(zr[lane])), g1 = silu_(bf2f(zr[lane + 64]));
  t[(size_t)row * 128 + lane] = f2bf(((v0 - mean) * rstd * ow[k * 128 + lane] + ob[k * 128 + lane]) * g0);
  t[(size_t)row * 128 + lane + 64] = f2bf(((v1 - mean) * rstd * ow[k * 128 + lane + 64] + ob[k * 128 + lane + 64]) * g1);
}

// ---------------- K11: Wout GEMM + (skip * xh * se) epilogue ----------------
__global__ __launch_bounds__(256) void k_gemm_wout(const u16* __restrict__ t,
    const float* __restrict__ Wout, const u16* __restrict__ xs, const float* __restrict__ se,
    const float* __restrict__ skip, u16* __restrict__ xm2) {
  const int k = blockIdx.z;
  const int m0 = blockIdx.y * 64;
  const int n0 = blockIdx.x * 64;
  const u16* A = t + (size_t)k * M_ * 128;         // lda = 128
  const float* Bw = Wout + (size_t)k * 128 * 128;  // ldb = 128
  __shared__ float As[16][68];
  __shared__ float Bs[16][68];
  const int tid = threadIdx.x;
  const int tx = tid & 15, ty = tid >> 4;
  float acc[4][4] = {};
  for (int kk0 = 0; kk0 < 128; kk0 += 16) {
    {
      int r = tid >> 2, c4 = tid & 3;
      uint2 v = *(const uint2*)(A + (size_t)(m0 + r) * 128 + kk0 + c4 * 4);
      As[c4 * 4 + 0][r] = bflo(v.x); As[c4 * 4 + 1][r] = bfhi(v.x);
      As[c4 * 4 + 2][r] = bflo(v.y); As[c4 * 4 + 3][r] = bfhi(v.y);
    }
    {
      int r = tid >> 4, c4 = tid & 15;
      *(float4*)&Bs[r][c4 * 4] = *(const float4*)(Bw + (size_t)(kk0 + r) * 128 + n0 + c4 * 4);
    }
    __syncthreads();
    #pragma unroll
    for (int kk = 0; kk < 16; ++kk) {
      float a[4], b[4];
      *(float4*)a = *(const float4*)&As[kk][ty * 4];
      #pragma unroll
      for (int j = 0; j < 4; ++j) b[j] = Bs[kk][j * 16 + tx];
      #pragma unroll
      for (int i = 0; i < 4; ++i)
        #pragma unroll
        for (int j = 0; j < 4; ++j) acc[i][j] += a[i] * b[j];
    }
    __syncthreads();
  }
  const float sk = skip[0];
  #pragma unroll
  for (int i = 0; i < 4; ++i) {
    int m = m0 + ty * 4 + i;
    int b = m / L_;
    #pragma unroll
    for (int j = 0; j < 4; ++j) {
      int n = n0 + j * 16 + tx;
      int c = k * 128 + n;
      float v = acc[i][j] * sk * bf2f(xs[(size_t)m * C_ + c]) * se[b * C_ + c];
      xm2[(size_t)m * C_ + c] = f2bf(v);
    }
  }
}

// ---------------- K12: LN over C (rows of 512) ----------------
__global__ __launch_bounds__(256) void k_ln_rows512(const u16* __restrict__ in,
    const float* __restrict__ w, const float* __restrict__ bia, u16* __restrict__ outp) {
  const int row = blockIdx.x * 4 + (threadIdx.x >> 6);
  const int lane = threadIdx.x & 63;
  const u16* r = in + (size_t)row * C_;
  float v[8];
  float s1 = 0.f, s2 = 0.f;
  #pragma unroll
  for (int i = 0; i < 8; ++i) { v[i] = bf2f(r[lane + i * 64]); s1 += v[i]; s2 += v[i] * v[i]; }
  #pragma unroll
  for (int o = 32; o; o >>= 1) { s1 += __shfl_xor(s1, o, 64); s2 += __shfl_xor(s2, o, 64); }
  float mean = s1 * (1.f / C_);
  float rstd = rsqrtf(s2 * (1.f / C_) - mean * mean + 1e-5f);
  #pragma unroll
  for (int i = 0; i < 8; ++i) {
    int c = lane + i * 64;
    outp[(size_t)row * C_ + c] = f2bf((v[i] - mean) * rstd * w[c] + bia[c]);
  }
}

// ---------------- K13: proj GEMM + bias, transposed write to (B,C,H,W) ----------------
__global__ __launch_bounds__(256) void k_gemm_proj(const u16* __restrict__ xln,
    const float* __restrict__ projw, const float* __restrict__ projb, float* __restrict__ outp) {
  const int m0 = blockIdx.y * 64;
  const int n0 = blockIdx.x * 64;
  __shared__ float As[16][68];
  __shared__ float Bs[16][68];
  __shared__ float outs[64][65];
  const int tid = threadIdx.x;
  const int tx = tid & 15, ty = tid >> 4;
  float acc[4][4] = {};
  for (int kk0 = 0; kk0 < 512; kk0 += 16) {
    {
      int r = tid >> 2, c4 = tid & 3;
      uint2 v = *(const uint2*)(xln + (size_t)(m0 + r) * 512 + kk0 + c4 * 4);
      As[c4 * 4 + 0][r] = bflo(v.x); As[c4 * 4 + 1][r] = bfhi(v.x);
      As[c4 * 4 + 2][r] = bflo(v.y); As[c4 * 4 + 3][r] = bfhi(v.y);
    }
    {
      int r = tid >> 4, c4 = tid & 15;
      *(float4*)&Bs[r][c4 * 4] = *(const float4*)(projw + (size_t)(kk0 + r) * 512 + n0 + c4 * 4);
    }
    __syncthreads();
    #pragma unroll
    for (int kk = 0; kk < 16; ++kk) {
      float a[4], b[4];
      *(float4*)a = *(const float4*)&As[kk][ty * 4];
      #pragma unroll
      for (int j = 0; j < 4; ++j) b[j] = Bs[kk][j * 16 + tx];
      #pragma unroll
      for (int i = 0; i < 4; ++i)
        #pragma unroll
        for (int j = 0; j < 4; ++j) acc[i][j] += a[i] * b[j];
    }
    __syncthreads();
  }
  #pragma unroll
  for (int i = 0; i < 4; ++i)
    #pragma unroll
    for (int j = 0; j < 4; ++j) {
      int n = n0 + j * 16 + tx;
      outs[n - n0][ty * 4 + i] = acc[i][j] + projb[n];
    }
  __syncthreads();
  const int b = m0 / L_;
  const int sp0 = m0 % L_;
  for (int idx = tid; idx < 64 * 64; idx += 256) {
    int n = idx >> 6, mi = idx & 63;
    outp[((size_t)b * C_ + n0 + n) * L_ + sp0 + mi] = outs[n][mi];
  }
}

extern "C" void kernel_launch(void* const* d_in, const int* in_sizes, int n_in,
                              void* d_out, int out_size, void* d_ws, size_t ws_size,
                              hipStream_t stream) {
  const float* x     = (const float*)d_in[0];
  const float* nw    = (const float*)d_in[1];
  const float* nb    = (const float*)d_in[2];
  const float* fc1w  = (const float*)d_in[3];
  const float* fc1b  = (const float*)d_in[4];
  const float* fc2w  = (const float*)d_in[5];
  const float* fc2b  = (const float*)d_in[6];
  const float* Win   = (const float*)d_in[7];
  const float* convw = (const float*)d_in[8];
  const float* convb = (const float*)d_in[9];
  const float* Wx    = (const float*)d_in[10];
  const float* Wdt   = (const float*)d_in[11];
  const float* dtb   = (const float*)d_in[12];
  const float* Alog  = (const float*)d_in[13];
  const float* Dp    = (const float*)d_in[14];
  const float* onw   = (const float*)d_in[15];
  const float* onb   = (const float*)d_in[16];
  const float* Wout  = (const float*)d_in[17];
  const float* projw = (const float*)d_in[18];
  const float* projb = (const float*)d_in[19];
  const float* skip  = (const float*)d_in[20];
  float* outp = (float*)d_out;

  const size_t BIGE = (size_t)4 * B_ * L_ * 128;   // 18,874,368 elements
  char* p = (char*)d_ws;
  auto carve = [&](size_t bytes) { char* r = p; p += (bytes + 255) & ~(size_t)255; return r; };
  u16*   xs    = (u16*)  carve(BIGE * 2);          // (B,L,C) bf16
  u16*   big1  = (u16*)  carve(BIGE * 2);          // xin -> y -> xln
  u16*   big2  = (u16*)  carve(BIGE * 2);          // zbuf -> xm2
  u16*   big3  = (u16*)  carve(BIGE * 2);          // xc -> t
  float* xdbl  = (float*)carve((size_t)2359296 * 4);
  float* segA  = (float*)carve((size_t)147456 * 4);
  float* segB  = (float*)carve((size_t)147456 * 4);
  float* hpre  = (float*)carve((size_t)147456 * 4);
  float* zpart = (float*)carve((size_t)147456 * 4);
  float* z     = (float*)carve((size_t)8192 * 4);
  float* se    = (float*)carve((size_t)8192 * 4);

  k_ln_in<<<dim3(L_ / 16, B_), 256, 0, stream>>>(x, nw, nb, xs);
  k_colsum_part<<<dim3(2, B_, 18), 256, 0, stream>>>(xs, zpart);
  k_colsum_fin<<<dim3(2, B_), 256, 0, stream>>>(zpart, z);
  k_se<<<B_, 256, 0, stream>>>(z, fc1w, fc1b, fc2w, fc2b, se);
  k_gemm_xz<<<dim3(4, M_ / 64, 4), 256, 0, stream>>>(xs, Win, big1, big2);
  k_dwconv<<<dim3(L_ / 2, 64), 256, 0, stream>>>(big1, convw, convb, big3);
  k_xdbl<<<dim3(L_ / 256, 64), 256, 0, stream>>>(big3, Wx, xdbl);
  k_scan_passA<<<dim3(SEG_, 64), 128, 0, stream>>>(big3, xdbl, Wdt, dtb, Alog, segA, segB);
  k_scan_passB<<<64, 128, 0, stream>>>(segA, segB, hpre);
  k_scan_passC<<<dim3(SEG_, 64), 128, 0, stream>>>(big3, xdbl, Wdt, dtb, Alog, Dp, hpre, big1);
  k_gate_ln<<<M_ * 4 / 4, 256, 0, stream>>>(big1, big2, onw, onb, big3);
  k_gemm_wout<<<dim3(2, M_ / 64, 4), 256, 0, stream>>>(big3, Wout, xs, se, skip, big2);
  k_ln_rows512<<<M_ / 4, 256, 0, stream>>>(big2, nw, nb, big1);
  k_gemm_proj<<<dim3(8, M_ / 64), 256, 0, stream>>>(big1, projw, projb, outp);
}

// Round 3
// 576.951 us; speedup vs baseline: 1.6449x; 1.6449x over previous
//
#include <hip/hip_runtime.h>
#include <math.h>

#define DEV static __device__ __forceinline__

typedef unsigned int  u32;
typedef unsigned short u16;

using bf16x8 = __attribute__((ext_vector_type(8))) __bf16;
using f32x4  = __attribute__((ext_vector_type(4))) float;

static constexpr int B_ = 16;
static constexpr int C_ = 512;
static constexpr int H_ = 48;
static constexpr int W_ = 48;
static constexpr int L_ = 2304;      // H*W
static constexpr int M_ = B_ * L_;   // 36864
static constexpr int SEG_ = 18;      // scan segments
static constexpr int TSEG_ = 128;    // 18*128 = 2304

DEV float silu_(float v) { return v / (1.f + __expf(-v)); }
DEV float bflo(u32 p) { return __uint_as_float(p << 16); }
DEV float bfhi(u32 p) { return __uint_as_float(p & 0xffff0000u); }
DEV float bf2f(u16 v) { return __uint_as_float(((u32)v) << 16); }
DEV u16 f2bf(float f) { u32 u = __float_as_uint(f); u32 r = u + 0x7fffu + ((u >> 16) & 1u); return (u16)(r >> 16); }

// sequence position l (direction k) -> spatial index sp = h*W + w
DEV int seq_to_sp(int k, int l) {
  int ll = (k & 1) ? (L_ - 1 - l) : l;
  if (k >= 2) return (ll % H_) * W_ + (ll / H_);   // l = w*H + h
  return ll;
}

// ================= MFMA GEMM helpers (128x128 tile, BK=64, 4 waves) =================
// LDS tile layout: [128 rows][64 bf16 = 128B] with T2 XOR swizzle: byte ^= (row&7)<<4.
DEV void stage_tile(u16* Ls, const u16* __restrict__ g, int ld) {
  const int tid = threadIdx.x;
  #pragma unroll
  for (int i = 0; i < 4; ++i) {
    int c = i * 256 + tid;            // 1024 chunks of 16B
    int row = c >> 3, slot = c & 7;
    uint4 v = *(const uint4*)(g + (size_t)row * ld + slot * 8);
    int b = row * 128 + ((slot * 16) ^ ((row & 7) << 4));
    *(uint4*)((char*)Ls + b) = v;
  }
}

DEV bf16x8 lds_frag(const u16* Ls, int row, int kbyte) {
  int b = row * 128 + (kbyte ^ ((row & 7) << 4));
  return *(const bf16x8*)((const char*)Ls + b);
}

// ---------------- K0: weight prep: transpose + bf16 convert ----------------
__global__ __launch_bounds__(256) void k_prep(const float* __restrict__ Win,
    const float* __restrict__ Wout, const float* __restrict__ projw,
    u16* __restrict__ WinT, u16* __restrict__ WoutT, u16* __restrict__ projwT) {
  int id = blockIdx.x * 256 + threadIdx.x;
  if (id < 131072) {                       // Win [4][128][256] -> WinT [4][256][128]
    int k = id >> 15, rem = id & 32767;
    int r = rem >> 8, n = rem & 255;
    WinT[(k << 15) + n * 128 + r] = f2bf(Win[id]);
  } else if (id < 196608) {                // Wout [4][128][128] -> WoutT [4][128][128] (T per k)
    int t = id - 131072;
    int k = t >> 14, rem = t & 16383;
    int r = rem >> 7, n = rem & 127;
    WoutT[(k << 14) + n * 128 + r] = f2bf(Wout[t]);
  } else {                                 // projw [512][512] -> projwT [512][512]
    int t = id - 196608;
    int r = t >> 9, n = t & 511;
    projwT[n * 512 + r] = f2bf(projw[t]);
  }
}

// ---------------- K1: layernorm over C of x transposed to (B,L,C), bf16 out ----------------
__global__ __launch_bounds__(256) void k_ln_in(const float* __restrict__ x,
    const float* __restrict__ w, const float* __restrict__ bia, u16* __restrict__ xs) {
  __shared__ float tile[16 * 513];
  __shared__ float smean[16], srstd[16];
  const int b = blockIdx.y;
  const int l0 = blockIdx.x * 16;
  const int tid = threadIdx.x;
  const float* xb = x + (size_t)b * C_ * L_;
  for (int idx = tid; idx < C_ * 16; idx += 256) {
    int c = idx >> 4, lt = idx & 15;
    tile[lt * 513 + c] = xb[(size_t)c * L_ + l0 + lt];
  }
  __syncthreads();
  {
    const int j = tid & 15, g = tid >> 4;
    float s1 = 0.f, s2 = 0.f;
    #pragma unroll
    for (int i = 0; i < 32; ++i) {
      float v = tile[g * 513 + j + i * 16];
      s1 += v; s2 += v * v;
    }
    #pragma unroll
    for (int o = 8; o; o >>= 1) { s1 += __shfl_xor(s1, o, 16); s2 += __shfl_xor(s2, o, 16); }
    if (j == 0) {
      float mean = s1 * (1.f / C_);
      float var = s2 * (1.f / C_) - mean * mean;
      smean[g] = mean;
      srstd[g] = rsqrtf(var + 1e-5f);
    }
  }
  __syncthreads();
  for (int idx = tid; idx < 16 * C_; idx += 256) {
    int lt = idx >> 9, c = idx & 511;
    float v = (tile[lt * 513 + c] - smean[lt]) * srstd[lt] * w[c] + bia[c];
    xs[((size_t)b * L_ + l0 + lt) * C_ + c] = f2bf(v);
  }
}

// ---------------- K2: column means for SE ----------------
__global__ __launch_bounds__(256) void k_colsum_part(const u16* __restrict__ xs, float* __restrict__ zpart) {
  const int c = blockIdx.x * 256 + threadIdx.x;
  const int b = blockIdx.y;
  const int s = blockIdx.z;
  float acc = 0.f;
  const u16* p = xs + ((size_t)b * L_ + s * 128) * C_ + c;
  for (int l = 0; l < 128; ++l) acc += bf2f(p[(size_t)l * C_]);
  zpart[((size_t)b * 18 + s) * C_ + c] = acc;
}

__global__ __launch_bounds__(256) void k_colsum_fin(const float* __restrict__ zpart, float* __restrict__ z) {
  const int c = blockIdx.x * 256 + threadIdx.x;
  const int b = blockIdx.y;
  float acc = 0.f;
  for (int s = 0; s < 18; ++s) acc += zpart[((size_t)b * 18 + s) * C_ + c];
  z[b * C_ + c] = acc * (1.f / L_);
}

// ---------------- K3: SE MLP ----------------
__global__ __launch_bounds__(256) void k_se(const float* __restrict__ z,
    const float* __restrict__ fc1w, const float* __restrict__ fc1b,
    const float* __restrict__ fc2w, const float* __restrict__ fc2b, float* __restrict__ se) {
  __shared__ float zs[512];
  __shared__ float hs[32];
  const int b = blockIdx.x, tid = threadIdx.x;
  zs[tid] = z[b * C_ + tid];
  zs[tid + 256] = z[b * C_ + tid + 256];
  __syncthreads();
  if (tid < 32) {
    float a = fc1b[tid];
    for (int c = 0; c < 512; ++c) a += zs[c] * fc1w[c * 32 + tid];
    hs[tid] = fmaxf(a, 0.f);
  }
  __syncthreads();
  for (int c = tid; c < 512; c += 256) {
    float a = fc2b[c];
    #pragma unroll
    for (int r = 0; r < 32; ++r) a += hs[r] * fc2w[r * 512 + c];
    se[b * C_ + c] = 1.f / (1.f + __expf(-a));
  }
}

// ---------------- K4: xz GEMM (MFMA): xs[:, k*128:+128] @ Win[k] ----------------
__global__ __launch_bounds__(256) void k_gemm_xz(const u16* __restrict__ xs,
    const u16* __restrict__ WinT, u16* __restrict__ xin, u16* __restrict__ zbuf) {
  __shared__ u16 lds[16384];
  u16* As = lds; u16* Bs = lds + 8192;
  const int k = blockIdx.z;
  const int nb = blockIdx.x;              // 0 -> xin, 1 -> zbuf
  const int m0 = blockIdx.y * 128;
  const int tid = threadIdx.x, l = tid & 63, w = tid >> 6;
  const int wm = w >> 1, wn = w & 1;
  const int fr = l & 15, fg = l >> 4;
  f32x4 acc[4][4];
  #pragma unroll
  for (int mi = 0; mi < 4; ++mi)
    #pragma unroll
    for (int ni = 0; ni < 4; ++ni) acc[mi][ni] = (f32x4){0.f, 0.f, 0.f, 0.f};
  const u16* Ag = xs + (size_t)m0 * 512 + k * 128;
  const u16* Bg = WinT + (size_t)k * 32768 + (size_t)nb * 16384;
  #pragma unroll
  for (int kk0 = 0; kk0 < 128; kk0 += 64) {
    stage_tile(As, Ag + kk0, 512);
    stage_tile(Bs, Bg + kk0, 128);
    __syncthreads();
    bf16x8 af[2][4], bfr[2][4];
    #pragma unroll
    for (int h = 0; h < 2; ++h)
      #pragma unroll
      for (int s = 0; s < 4; ++s) {
        af[h][s]  = lds_frag(As, wm * 64 + s * 16 + fr, h * 64 + fg * 16);
        bfr[h][s] = lds_frag(Bs, wn * 64 + s * 16 + fr, h * 64 + fg * 16);
      }
    #pragma unroll
    for (int h = 0; h < 2; ++h)
      #pragma unroll
      for (int mi = 0; mi < 4; ++mi)
        #pragma unroll
        for (int ni = 0; ni < 4; ++ni)
          acc[mi][ni] = __builtin_amdgcn_mfma_f32_16x16x32_bf16(af[h][mi], bfr[h][ni], acc[mi][ni], 0, 0, 0);
    __syncthreads();
  }
  // epilogue: stage bf16 C tile, coalesced row writes
  #pragma unroll
  for (int mi = 0; mi < 4; ++mi)
    #pragma unroll
    for (int ni = 0; ni < 4; ++ni)
      #pragma unroll
      for (int j = 0; j < 4; ++j)
        lds[(wm * 64 + mi * 16 + fg * 4 + j) * 128 + wn * 64 + ni * 16 + fr] = f2bf(acc[mi][ni][j]);
  __syncthreads();
  u16* dst = (nb == 0 ? xin : zbuf) + ((size_t)k * M_ + m0) * 128;
  for (int idx = tid; idx < 128 * 16; idx += 256) {
    int row = idx >> 4, q = idx & 15;
    *(uint4*)&dst[(size_t)row * 128 + q * 8] = *(const uint4*)&lds[row * 128 + q * 8];
  }
}

// ---------------- K5: depthwise 3x3 conv + bias + silu ----------------
__global__ __launch_bounds__(256) void k_dwconv(const u16* __restrict__ xin,
    const float* __restrict__ cw, const float* __restrict__ cb, u16* __restrict__ xc) {
  const int kb = blockIdx.y;
  const int k = kb >> 4;
  const int tid = threadIdx.x;
  const int dc = tid & 127, si = tid >> 7;
  const int sp = blockIdx.x * 2 + si;
  const int h = sp / W_, w = sp % W_;
  const float* wp = cw + ((size_t)k * 128 + dc) * 9;
  float tap[9];
  #pragma unroll
  for (int t = 0; t < 9; ++t) tap[t] = wp[t];
  float acc = cb[k * 128 + dc];
  const u16* base = xin + (size_t)kb * L_ * 128 + dc;
  #pragma unroll
  for (int dy = -1; dy <= 1; ++dy) {
    int hh = h + dy;
    if (hh < 0 || hh >= H_) continue;
    #pragma unroll
    for (int dx = -1; dx <= 1; ++dx) {
      int ww = w + dx;
      if (ww < 0 || ww >= W_) continue;
      acc += tap[(dy + 1) * 3 + dx + 1] * bf2f(base[(size_t)(hh * W_ + ww) * 128]);
    }
  }
  xc[((size_t)kb * L_ + sp) * 128 + dc] = f2bf(silu_(acc));
}

// ---------------- K6: x_dbl = Wx[k] @ u ----------------
__global__ __launch_bounds__(256) void k_xdbl(const u16* __restrict__ xc,
    const float* __restrict__ Wx, float* __restrict__ xdbl) {
  __shared__ float wx[10 * 128];
  const int kb = blockIdx.y;
  const int k = kb >> 4;
  const int sp = blockIdx.x * 256 + threadIdx.x;
  for (int i = threadIdx.x; i < 1280; i += 256) wx[i] = Wx[(size_t)k * 1280 + i];
  __syncthreads();
  float acc[10] = {};
  const u16* up = xc + ((size_t)kb * L_ + sp) * 128;
  for (int q = 0; q < 16; ++q) {
    uint4 v = *(const uint4*)(up + q * 8);
    float e[8] = {bflo(v.x), bfhi(v.x), bflo(v.y), bfhi(v.y),
                  bflo(v.z), bfhi(v.z), bflo(v.w), bfhi(v.w)};
    #pragma unroll
    for (int r = 0; r < 10; ++r) {
      const float* wr = &wx[r * 128 + q * 8];
      #pragma unroll
      for (int j = 0; j < 8; ++j) acc[r] += wr[j] * e[j];
    }
  }
  float* o = xdbl + ((size_t)kb * L_ + sp) * 16;
  #pragma unroll
  for (int r = 0; r < 10; ++r) o[r] = acc[r];
}

// ---------------- scan element ----------------
DEV void scan_elem(const float* __restrict__ xr, const float wdt[8], float bias, float Aa,
                   float u, float& dA, float& dBu, float& Cm) {
  float4 q0 = *(const float4*)(xr);
  float4 q1 = *(const float4*)(xr + 4);
  float4 q2 = *(const float4*)(xr + 8);
  float dt = bias + wdt[0] * q0.x + wdt[1] * q0.y + wdt[2] * q0.z + wdt[3] * q0.w
                  + wdt[4] * q1.x + wdt[5] * q1.y + wdt[6] * q1.z + wdt[7] * q1.w;
  float delta = (dt > 20.f) ? dt : log1pf(__expf(dt));
  dA = __expf(delta * Aa);
  dBu = delta * u * q2.x;
  Cm = q2.y;
}

// ---------------- K7: scan pass A ----------------
__global__ __launch_bounds__(128) void k_scan_passA(const u16* __restrict__ xc,
    const float* __restrict__ xdbl, const float* __restrict__ Wdt, const float* __restrict__ dtb,
    const float* __restrict__ Alog, float* __restrict__ segA, float* __restrict__ segB) {
  const int kb = blockIdx.y;
  const int k = kb >> 4;
  const int s = blockIdx.x;
  const int dc = threadIdx.x;
  float wdt[8];
  #pragma unroll
  for (int r = 0; r < 8; ++r) wdt[r] = Wdt[((size_t)k * 128 + dc) * 8 + r];
  const float bias = dtb[k * 128 + dc];
  const float Aa = -__expf(Alog[k * 128 + dc]);
  float a = 1.f, bacc = 0.f;
  #pragma unroll 4
  for (int i = 0; i < TSEG_; ++i) {
    int l = s * TSEG_ + i;
    int sp = seq_to_sp(k, l);
    const float* xr = xdbl + ((size_t)kb * L_ + sp) * 16;
    float u = bf2f(xc[((size_t)kb * L_ + sp) * 128 + dc]);
    float dA, dBu, Cm;
    scan_elem(xr, wdt, bias, Aa, u, dA, dBu, Cm);
    a *= dA;
    bacc = dA * bacc + dBu;
  }
  segA[((size_t)kb * SEG_ + s) * 128 + dc] = a;
  segB[((size_t)kb * SEG_ + s) * 128 + dc] = bacc;
}

// ---------------- K8: scan pass B ----------------
__global__ __launch_bounds__(128) void k_scan_passB(const float* __restrict__ segA,
    const float* __restrict__ segB, float* __restrict__ hpre) {
  const int kb = blockIdx.x;
  const int dc = threadIdx.x;
  float h = 0.f;
  for (int s = 0; s < SEG_; ++s) {
    size_t o = ((size_t)kb * SEG_ + s) * 128 + dc;
    hpre[o] = h;
    h = segA[o] * h + segB[o];
  }
}

// ---------------- K9: scan pass C ----------------
__global__ __launch_bounds__(128) void k_scan_passC(const u16* __restrict__ xc,
    const float* __restrict__ xdbl, const float* __restrict__ Wdt, const float* __restrict__ dtb,
    const float* __restrict__ Alog, const float* __restrict__ Dp, const float* __restrict__ hpre,
    u16* __restrict__ y) {
  const int kb = blockIdx.y;
  const int k = kb >> 4;
  const int s = blockIdx.x;
  const int dc = threadIdx.x;
  float wdt[8];
  #pragma unroll
  for (int r = 0; r < 8; ++r) wdt[r] = Wdt[((size_t)k * 128 + dc) * 8 + r];
  const float bias = dtb[k * 128 + dc];
  const float Aa = -__expf(Alog[k * 128 + dc]);
  const float Dv = Dp[k * 128 + dc];
  float h = hpre[((size_t)kb * SEG_ + s) * 128 + dc];
  #pragma unroll 4
  for (int i = 0; i < TSEG_; ++i) {
    int l = s * TSEG_ + i;
    int sp = seq_to_sp(k, l);
    const float* xr = xdbl + ((size_t)kb * L_ + sp) * 16;
    float u = bf2f(xc[((size_t)kb * L_ + sp) * 128 + dc]);
    float dA, dBu, Cm;
    scan_elem(xr, wdt, bias, Aa, u, dA, dBu, Cm);
    h = dA * h + dBu;
    y[((size_t)kb * L_ + sp) * 128 + dc] = f2bf(h * Cm + Dv * u);
  }
}

// ---------------- K10: LN over d (onorm) + silu(z) gate ----------------
__global__ __launch_bounds__(256) void k_gate_ln(const u16* __restrict__ y,
    const u16* __restrict__ zbuf, const float* __restrict__ ow, const float* __restrict__ ob,
    u16* __restrict__ t) {
  const int row = blockIdx.x * 4 + (threadIdx.x >> 6);
  const int lane = threadIdx.x & 63;
  const int kb = row / L_;
  const int k = kb >> 4;
  const u16* yr = y + (size_t)row * 128;
  float v0 = bf2f(yr[lane]), v1 = bf2f(yr[lane + 64]);
  float s1 = v0 + v1, s2 = v0 * v0 + v1 * v1;
  #pragma unroll
  for (int o = 32; o; o >>= 1) { s1 += __shfl_xor(s1, o, 64); s2 += __shfl_xor(s2, o, 64); }
  float mean = s1 * (1.f / 128.f);
  float rstd = rsqrtf(s2 * (1.f / 128.f) - mean * mean + 1e-5f);
  const u16* zr = zbuf + (size_t)row * 128;
  float g0 = silu_(bf2f(zr[lane])), g1 = silu_(bf2f(zr[lane + 64]));
  t[(size_t)row * 128 + lane] = f2bf(((v0 - mean) * rstd * ow[k * 128 + lane] + ob[k * 128 + lane]) * g0);
  t[(size_t)row * 128 + lane + 64] = f2bf(((v1 - mean) * rstd * ow[k * 128 + lane + 64] + ob[k * 128 + lane + 64]) * g1);
}

// ---------------- K11: Wout GEMM (MFMA) + (skip * xh * se) epilogue ----------------
__global__ __launch_bounds__(256) void k_gemm_wout(const u16* __restrict__ t,
    const u16* __restrict__ WoutT, const u16* __restrict__ xs, const float* __restrict__ se,
    const float* __restrict__ skip, u16* __restrict__ xm2) {
  __shared__ u16 lds[16384];
  u16* As = lds; u16* Bs = lds + 8192;
  const int k = blockIdx.z;
  const int m0 = blockIdx.y * 128;
  const int tid = threadIdx.x, l = tid & 63, w = tid >> 6;
  const int wm = w >> 1, wn = w & 1;
  const int fr = l & 15, fg = l >> 4;
  f32x4 acc[4][4];
  #pragma unroll
  for (int mi = 0; mi < 4; ++mi)
    #pragma unroll
    for (int ni = 0; ni < 4; ++ni) acc[mi][ni] = (f32x4){0.f, 0.f, 0.f, 0.f};
  const u16* Ag = t + ((size_t)k * M_ + m0) * 128;
  const u16* Bg = WoutT + (size_t)k * 16384;
  #pragma unroll
  for (int kk0 = 0; kk0 < 128; kk0 += 64) {
    stage_tile(As, Ag + kk0, 128);
    stage_tile(Bs, Bg + kk0, 128);
    __syncthreads();
    bf16x8 af[2][4], bfr[2][4];
    #pragma unroll
    for (int h = 0; h < 2; ++h)
      #pragma unroll
      for (int s = 0; s < 4; ++s) {
        af[h][s]  = lds_frag(As, wm * 64 + s * 16 + fr, h * 64 + fg * 16);
        bfr[h][s] = lds_frag(Bs, wn * 64 + s * 16 + fr, h * 64 + fg * 16);
      }
    #pragma unroll
    for (int h = 0; h < 2; ++h)
      #pragma unroll
      for (int mi = 0; mi < 4; ++mi)
        #pragma unroll
        for (int ni = 0; ni < 4; ++ni)
          acc[mi][ni] = __builtin_amdgcn_mfma_f32_16x16x32_bf16(af[h][mi], bfr[h][ni], acc[mi][ni], 0, 0, 0);
    __syncthreads();
  }
  #pragma unroll
  for (int mi = 0; mi < 4; ++mi)
    #pragma unroll
    for (int ni = 0; ni < 4; ++ni)
      #pragma unroll
      for (int j = 0; j < 4; ++j)
        lds[(wm * 64 + mi * 16 + fg * 4 + j) * 128 + wn * 64 + ni * 16 + fr] = f2bf(acc[mi][ni][j]);
  __syncthreads();
  const float sk = skip[0];
  const int b = m0 / L_;
  for (int idx = tid; idx < 128 * 16; idx += 256) {
    int row = idx >> 4, q = idx & 15;
    int m = m0 + row, c = k * 128 + q * 8;
    uint4 cv = *(const uint4*)&lds[row * 128 + q * 8];
    uint4 xv = *(const uint4*)&xs[(size_t)m * 512 + c];
    float4 s0 = *(const float4*)&se[b * 512 + c];
    float4 s1 = *(const float4*)&se[b * 512 + c + 4];
    float o[8];
    o[0] = bflo(cv.x) * sk * bflo(xv.x) * s0.x;
    o[1] = bfhi(cv.x) * sk * bfhi(xv.x) * s0.y;
    o[2] = bflo(cv.y) * sk * bflo(xv.y) * s0.z;
    o[3] = bfhi(cv.y) * sk * bfhi(xv.y) * s0.w;
    o[4] = bflo(cv.z) * sk * bflo(xv.z) * s1.x;
    o[5] = bfhi(cv.z) * sk * bfhi(xv.z) * s1.y;
    o[6] = bflo(cv.w) * sk * bflo(xv.w) * s1.z;
    o[7] = bfhi(cv.w) * sk * bfhi(xv.w) * s1.w;
    u16 ov[8];
    #pragma unroll
    for (int j = 0; j < 8; ++j) ov[j] = f2bf(o[j]);
    *(uint4*)&xm2[(size_t)m * 512 + c] = *(const uint4*)ov;
  }
}

// ---------------- K12: LN over C (rows of 512) ----------------
__global__ __launch_bounds__(256) void k_ln_rows512(const u16* __restrict__ in,
    const float* __restrict__ w, const float* __restrict__ bia, u16* __restrict__ outp) {
  const int row = blockIdx.x * 4 + (threadIdx.x >> 6);
  const int lane = threadIdx.x & 63;
  const u16* r = in + (size_t)row * C_;
  float v[8];
  float s1 = 0.f, s2 = 0.f;
  #pragma unroll
  for (int i = 0; i < 8; ++i) { v[i] = bf2f(r[lane + i * 64]); s1 += v[i]; s2 += v[i] * v[i]; }
  #pragma unroll
  for (int o = 32; o; o >>= 1) { s1 += __shfl_xor(s1, o, 64); s2 += __shfl_xor(s2, o, 64); }
  float mean = s1 * (1.f / C_);
  float rstd = rsqrtf(s2 * (1.f / C_) - mean * mean + 1e-5f);
  #pragma unroll
  for (int i = 0; i < 8; ++i) {
    int c = lane + i * 64;
    outp[(size_t)row * C_ + c] = f2bf((v[i] - mean) * rstd * w[c] + bia[c]);
  }
}

// ---------------- K13: proj GEMM (MFMA) + bias, transposed write to (B,C,H,W) ----------------
__global__ __launch_bounds__(256) void k_gemm_proj(const u16* __restrict__ xln,
    const u16* __restrict__ projwT, const float* __restrict__ projb, float* __restrict__ outp) {
  __shared__ float ldsp[8448];                 // 33792B: tiles (32KB) / out-stage 64x132 f32
  u16* As = (u16*)ldsp; u16* Bs = As + 8192;
  const int n0 = blockIdx.x * 128;
  const int m0 = blockIdx.y * 128;
  const int tid = threadIdx.x, l = tid & 63, w = tid >> 6;
  const int wm = w >> 1, wn = w & 1;
  const int fr = l & 15, fg = l >> 4;
  f32x4 acc[4][4];
  #pragma unroll
  for (int mi = 0; mi < 4; ++mi)
    #pragma unroll
    for (int ni = 0; ni < 4; ++ni) acc[mi][ni] = (f32x4){0.f, 0.f, 0.f, 0.f};
  const u16* Ag = xln + (size_t)m0 * 512;
  const u16* Bg = projwT + (size_t)n0 * 512;
  for (int kk0 = 0; kk0 < 512; kk0 += 64) {
    stage_tile(As, Ag + kk0, 512);
    stage_tile(Bs, Bg + kk0, 512);
    __syncthreads();
    bf16x8 af[2][4], bfr[2][4];
    #pragma unroll
    for (int h = 0; h < 2; ++h)
      #pragma unroll
      for (int s = 0; s < 4; ++s) {
        af[h][s]  = lds_frag(As, wm * 64 + s * 16 + fr, h * 64 + fg * 16);
        bfr[h][s] = lds_frag(Bs, wn * 64 + s * 16 + fr, h * 64 + fg * 16);
      }
    #pragma unroll
    for (int h = 0; h < 2; ++h)
      #pragma unroll
      for (int mi = 0; mi < 4; ++mi)
        #pragma unroll
        for (int ni = 0; ni < 4; ++ni)
          acc[mi][ni] = __builtin_amdgcn_mfma_f32_16x16x32_bf16(af[h][mi], bfr[h][ni], acc[mi][ni], 0, 0, 0);
    __syncthreads();
  }
  // epilogue: transpose via LDS in two 64-col halves, fp32 coalesced writes over m
  const int b = m0 / L_, sp0 = m0 % L_;
  #pragma unroll
  for (int half = 0; half < 2; ++half) {
    if (wn == half) {
      #pragma unroll
      for (int ni = 0; ni < 4; ++ni) {
        int nl = ni * 16 + fr;
        float bias = projb[n0 + half * 64 + nl];
        #pragma unroll
        for (int mi = 0; mi < 4; ++mi)
          #pragma unroll
          for (int j = 0; j < 4; ++j)
            ldsp[nl * 132 + wm * 64 + mi * 16 + fg * 4 + j] = acc[mi][ni][j] + bias;
      }
    }
    __syncthreads();
    for (int idx = tid; idx < 64 * 32; idx += 256) {
      int n = idx >> 5, mq = idx & 31;
      float4 v = *(const float4*)&ldsp[n * 132 + mq * 4];
      *(float4*)&outp[((size_t)b * 512 + n0 + half * 64 + n) * L_ + sp0 + mq * 4] = v;
    }
    __syncthreads();
  }
}

extern "C" void kernel_launch(void* const* d_in, const int* in_sizes, int n_in,
                              void* d_out, int out_size, void* d_ws, size_t ws_size,
                              hipStream_t stream) {
  const float* x     = (const float*)d_in[0];
  const float* nw    = (const float*)d_in[1];
  const float* nb    = (const float*)d_in[2];
  const float* fc1w  = (const float*)d_in[3];
  const float* fc1b  = (const float*)d_in[4];
  const float* fc2w  = (const float*)d_in[5];
  const float* fc2b  = (const float*)d_in[6];
  const float* Win   = (const float*)d_in[7];
  const float* convw = (const float*)d_in[8];
  const float* convb = (const float*)d_in[9];
  const float* Wx    = (const float*)d_in[10];
  const float* Wdt   = (const float*)d_in[11];
  const float* dtb   = (const float*)d_in[12];
  const float* Alog  = (const float*)d_in[13];
  const float* Dp    = (const float*)d_in[14];
  const float* onw   = (const float*)d_in[15];
  const float* onb   = (const float*)d_in[16];
  const float* Wout  = (const float*)d_in[17];
  const float* projw = (const float*)d_in[18];
  const float* projb = (const float*)d_in[19];
  const float* skip  = (const float*)d_in[20];
  float* outp = (float*)d_out;

  const size_t BIGE = (size_t)4 * B_ * L_ * 128;   // 18,874,368 elements
  char* p = (char*)d_ws;
  auto carve = [&](size_t bytes) { char* r = p; p += (bytes + 255) & ~(size_t)255; return r; };
  u16*   xs     = (u16*)  carve(BIGE * 2);          // (B,L,C) bf16
  u16*   big1   = (u16*)  carve(BIGE * 2);          // xin -> y -> xln
  u16*   big2   = (u16*)  carve(BIGE * 2);          // zbuf -> xm2
  u16*   big3   = (u16*)  carve(BIGE * 2);          // xc -> t
  float* xdbl   = (float*)carve((size_t)2359296 * 4);
  float* segA   = (float*)carve((size_t)147456 * 4);
  float* segB   = (float*)carve((size_t)147456 * 4);
  float* hpre   = (float*)carve((size_t)147456 * 4);
  float* zpart  = (float*)carve((size_t)147456 * 4);
  float* z      = (float*)carve((size_t)8192 * 4);
  float* se     = (float*)carve((size_t)8192 * 4);
  u16*   WinT   = (u16*)  carve((size_t)131072 * 2);
  u16*   WoutT  = (u16*)  carve((size_t)65536 * 2);
  u16*   projwT = (u16*)  carve((size_t)262144 * 2);

  k_prep<<<1792, 256, 0, stream>>>(Win, Wout, projw, WinT, WoutT, projwT);
  k_ln_in<<<dim3(L_ / 16, B_), 256, 0, stream>>>(x, nw, nb, xs);
  k_colsum_part<<<dim3(2, B_, 18), 256, 0, stream>>>(xs, zpart);
  k_colsum_fin<<<dim3(2, B_), 256, 0, stream>>>(zpart, z);
  k_se<<<B_, 256, 0, stream>>>(z, fc1w, fc1b, fc2w, fc2b, se);
  k_gemm_xz<<<dim3(2, M_ / 128, 4), 256, 0, stream>>>(xs, WinT, big1, big2);
  k_dwconv<<<dim3(L_ / 2, 64), 256, 0, stream>>>(big1, convw, convb, big3);
  k_xdbl<<<dim3(L_ / 256, 64), 256, 0, stream>>>(big3, Wx, xdbl);
  k_scan_passA<<<dim3(SEG_, 64), 128, 0, stream>>>(big3, xdbl, Wdt, dtb, Alog, segA, segB);
  k_scan_passB<<<64, 128, 0, stream>>>(segA, segB, hpre);
  k_scan_passC<<<dim3(SEG_, 64), 128, 0, stream>>>(big3, xdbl, Wdt, dtb, Alog, Dp, hpre, big1);
  k_gate_ln<<<M_ * 4 / 4, 256, 0, stream>>>(big1, big2, onw, onb, big3);
  k_gemm_wout<<<dim3(1, M_ / 128, 4), 256, 0, stream>>>(big3, WoutT, xs, se, skip, big2);
  k_ln_rows512<<<M_ / 4, 256, 0, stream>>>(big2, nw, nb, big1);
  k_gemm_proj<<<dim3(4, M_ / 128), 256, 0, stream>>>(big1, projwT, projb, outp);
}

// Round 4
// 457.261 us; speedup vs baseline: 2.0755x; 1.2618x over previous
//
#include <hip/hip_runtime.h>
#include <math.h>

#define DEV static __device__ __forceinline__

typedef unsigned int  u32;
typedef unsigned short u16;

using bf16x8 = __attribute__((ext_vector_type(8))) __bf16;
using f32x4  = __attribute__((ext_vector_type(4))) float;

static constexpr int B_ = 16;
static constexpr int C_ = 512;
static constexpr int H_ = 48;
static constexpr int W_ = 48;
static constexpr int L_ = 2304;      // H*W
static constexpr int M_ = B_ * L_;   // 36864
static constexpr int SEG_ = 48;      // scan segments (2304 = 48*48)
static constexpr int TSEG_ = 48;

DEV float silu_(float v) { return v / (1.f + __expf(-v)); }
DEV float bflo(u32 p) { return __uint_as_float(p << 16); }
DEV float bfhi(u32 p) { return __uint_as_float(p & 0xffff0000u); }
DEV float bf2f(u16 v) { return __uint_as_float(((u32)v) << 16); }
DEV u16 f2bf(float f) { u32 u = __float_as_uint(f); u32 r = u + 0x7fffu + ((u >> 16) & 1u); return (u16)(r >> 16); }

// direction k, segment s (TSEG=48): sp = sp0 + step*i, i in [0,48)
DEV void seg_affine(int k, int s, int& sp0, int& step) {
  if (k == 0)      { sp0 = 48 * s;        step = 1;   }
  else if (k == 1) { sp0 = 2303 - 48 * s; step = -1;  }
  else if (k == 2) { sp0 = s;             step = 48;  }
  else             { sp0 = 2303 - s;      step = -48; }
}

// ================= MFMA GEMM helpers (128x128 tile, BK=64, 4 waves) =================
DEV void stage_tile(u16* Ls, const u16* __restrict__ g, int ld) {
  const int tid = threadIdx.x;
  #pragma unroll
  for (int i = 0; i < 4; ++i) {
    int c = i * 256 + tid;
    int row = c >> 3, slot = c & 7;
    uint4 v = *(const uint4*)(g + (size_t)row * ld + slot * 8);
    int b = row * 128 + ((slot * 16) ^ ((row & 7) << 4));
    *(uint4*)((char*)Ls + b) = v;
  }
}

DEV bf16x8 lds_frag(const u16* Ls, int row, int kbyte) {
  int b = row * 128 + (kbyte ^ ((row & 7) << 4));
  return *(const bf16x8*)((const char*)Ls + b);
}

// ---------------- K0: weight prep: transpose + bf16 convert ----------------
__global__ __launch_bounds__(256) void k_prep(const float* __restrict__ Win,
    const float* __restrict__ Wout, const float* __restrict__ projw,
    u16* __restrict__ WinT, u16* __restrict__ WoutT, u16* __restrict__ projwT) {
  int id = blockIdx.x * 256 + threadIdx.x;
  if (id < 131072) {
    int k = id >> 15, rem = id & 32767;
    int r = rem >> 8, n = rem & 255;
    WinT[(k << 15) + n * 128 + r] = f2bf(Win[id]);
  } else if (id < 196608) {
    int t = id - 131072;
    int k = t >> 14, rem = t & 16383;
    int r = rem >> 7, n = rem & 127;
    WoutT[(k << 14) + n * 128 + r] = f2bf(Wout[t]);
  } else {
    int t = id - 196608;
    int r = t >> 9, n = t & 511;
    projwT[n * 512 + r] = f2bf(projw[t]);
  }
}

// ---------------- K1: layernorm over C of x transposed to (B,L,C), bf16 out ----------------
__global__ __launch_bounds__(256) void k_ln_in(const float* __restrict__ x,
    const float* __restrict__ w, const float* __restrict__ bia, u16* __restrict__ xs) {
  __shared__ float tile[16 * 513];
  __shared__ float smean[16], srstd[16];
  const int b = blockIdx.y;
  const int l0 = blockIdx.x * 16;
  const int tid = threadIdx.x;
  const float* xb = x + (size_t)b * C_ * L_;
  for (int idx = tid; idx < C_ * 16; idx += 256) {
    int c = idx >> 4, lt = idx & 15;
    tile[lt * 513 + c] = xb[(size_t)c * L_ + l0 + lt];
  }
  __syncthreads();
  {
    const int j = tid & 15, g = tid >> 4;
    float s1 = 0.f, s2 = 0.f;
    #pragma unroll
    for (int i = 0; i < 32; ++i) {
      float v = tile[g * 513 + j + i * 16];
      s1 += v; s2 += v * v;
    }
    #pragma unroll
    for (int o = 8; o; o >>= 1) { s1 += __shfl_xor(s1, o, 16); s2 += __shfl_xor(s2, o, 16); }
    if (j == 0) {
      float mean = s1 * (1.f / C_);
      float var = s2 * (1.f / C_) - mean * mean;
      smean[g] = mean;
      srstd[g] = rsqrtf(var + 1e-5f);
    }
  }
  __syncthreads();
  for (int idx = tid; idx < 16 * C_; idx += 256) {
    int lt = idx >> 9, c = idx & 511;
    float v = (tile[lt * 513 + c] - smean[lt]) * srstd[lt] * w[c] + bia[c];
    xs[((size_t)b * L_ + l0 + lt) * C_ + c] = f2bf(v);
  }
}

// ---------------- K2: column means for SE ----------------
__global__ __launch_bounds__(256) void k_colsum_part(const u16* __restrict__ xs, float* __restrict__ zpart) {
  const int c = blockIdx.x * 256 + threadIdx.x;
  const int b = blockIdx.y;
  const int s = blockIdx.z;
  float acc = 0.f;
  const u16* p = xs + ((size_t)b * L_ + s * 128) * C_ + c;
  for (int l = 0; l < 128; ++l) acc += bf2f(p[(size_t)l * C_]);
  zpart[((size_t)b * 18 + s) * C_ + c] = acc;
}

__global__ __launch_bounds__(256) void k_colsum_fin(const float* __restrict__ zpart, float* __restrict__ z) {
  const int c = blockIdx.x * 256 + threadIdx.x;
  const int b = blockIdx.y;
  float acc = 0.f;
  for (int s = 0; s < 18; ++s) acc += zpart[((size_t)b * 18 + s) * C_ + c];
  z[b * C_ + c] = acc * (1.f / L_);
}

// ---------------- K3: SE MLP ----------------
__global__ __launch_bounds__(256) void k_se(const float* __restrict__ z,
    const float* __restrict__ fc1w, const float* __restrict__ fc1b,
    const float* __restrict__ fc2w, const float* __restrict__ fc2b, float* __restrict__ se) {
  __shared__ float zs[512];
  __shared__ float hs[32];
  const int b = blockIdx.x, tid = threadIdx.x;
  zs[tid] = z[b * C_ + tid];
  zs[tid + 256] = z[b * C_ + tid + 256];
  __syncthreads();
  if (tid < 32) {
    float a = fc1b[tid];
    for (int c = 0; c < 512; ++c) a += zs[c] * fc1w[c * 32 + tid];
    hs[tid] = fmaxf(a, 0.f);
  }
  __syncthreads();
  for (int c = tid; c < 512; c += 256) {
    float a = fc2b[c];
    #pragma unroll
    for (int r = 0; r < 32; ++r) a += hs[r] * fc2w[r * 512 + c];
    se[b * C_ + c] = 1.f / (1.f + __expf(-a));
  }
}

// ---------------- K4: xz GEMM (MFMA) ----------------
__global__ __launch_bounds__(256) void k_gemm_xz(const u16* __restrict__ xs,
    const u16* __restrict__ WinT, u16* __restrict__ xin, u16* __restrict__ zbuf) {
  __shared__ u16 lds[16384];
  u16* As = lds; u16* Bs = lds + 8192;
  const int k = blockIdx.z;
  const int nb = blockIdx.x;
  const int m0 = blockIdx.y * 128;
  const int tid = threadIdx.x, l = tid & 63, w = tid >> 6;
  const int wm = w >> 1, wn = w & 1;
  const int fr = l & 15, fg = l >> 4;
  f32x4 acc[4][4];
  #pragma unroll
  for (int mi = 0; mi < 4; ++mi)
    #pragma unroll
    for (int ni = 0; ni < 4; ++ni) acc[mi][ni] = (f32x4){0.f, 0.f, 0.f, 0.f};
  const u16* Ag = xs + (size_t)m0 * 512 + k * 128;
  const u16* Bg = WinT + (size_t)k * 32768 + (size_t)nb * 16384;
  #pragma unroll
  for (int kk0 = 0; kk0 < 128; kk0 += 64) {
    stage_tile(As, Ag + kk0, 512);
    stage_tile(Bs, Bg + kk0, 128);
    __syncthreads();
    bf16x8 af[2][4], bfr[2][4];
    #pragma unroll
    for (int h = 0; h < 2; ++h)
      #pragma unroll
      for (int s = 0; s < 4; ++s) {
        af[h][s]  = lds_frag(As, wm * 64 + s * 16 + fr, h * 64 + fg * 16);
        bfr[h][s] = lds_frag(Bs, wn * 64 + s * 16 + fr, h * 64 + fg * 16);
      }
    #pragma unroll
    for (int h = 0; h < 2; ++h)
      #pragma unroll
      for (int mi = 0; mi < 4; ++mi)
        #pragma unroll
        for (int ni = 0; ni < 4; ++ni)
          acc[mi][ni] = __builtin_amdgcn_mfma_f32_16x16x32_bf16(af[h][mi], bfr[h][ni], acc[mi][ni], 0, 0, 0);
    __syncthreads();
  }
  #pragma unroll
  for (int mi = 0; mi < 4; ++mi)
    #pragma unroll
    for (int ni = 0; ni < 4; ++ni)
      #pragma unroll
      for (int j = 0; j < 4; ++j)
        lds[(wm * 64 + mi * 16 + fg * 4 + j) * 128 + wn * 64 + ni * 16 + fr] = f2bf(acc[mi][ni][j]);
  __syncthreads();
  u16* dst = (nb == 0 ? xin : zbuf) + ((size_t)k * M_ + m0) * 128;
  for (int idx = tid; idx < 128 * 16; idx += 256) {
    int row = idx >> 4, q = idx & 15;
    *(uint4*)&dst[(size_t)row * 128 + q * 8] = *(const uint4*)&lds[row * 128 + q * 8];
  }
}

// ---------------- K5: depthwise 3x3 conv + bias + silu ----------------
__global__ __launch_bounds__(256) void k_dwconv(const u16* __restrict__ xin,
    const float* __restrict__ cw, const float* __restrict__ cb, u16* __restrict__ xc) {
  const int kb = blockIdx.y;
  const int k = kb >> 4;
  const int tid = threadIdx.x;
  const int dc = tid & 127, si = tid >> 7;
  const int sp = blockIdx.x * 2 + si;
  const int h = sp / W_, w = sp % W_;
  const float* wp = cw + ((size_t)k * 128 + dc) * 9;
  float tap[9];
  #pragma unroll
  for (int t = 0; t < 9; ++t) tap[t] = wp[t];
  float acc = cb[k * 128 + dc];
  const u16* base = xin + (size_t)kb * L_ * 128 + dc;
  #pragma unroll
  for (int dy = -1; dy <= 1; ++dy) {
    int hh = h + dy;
    if (hh < 0 || hh >= H_) continue;
    #pragma unroll
    for (int dx = -1; dx <= 1; ++dx) {
      int ww = w + dx;
      if (ww < 0 || ww >= W_) continue;
      acc += tap[(dy + 1) * 3 + dx + 1] * bf2f(base[(size_t)(hh * W_ + ww) * 128]);
    }
  }
  xc[((size_t)kb * L_ + sp) * 128 + dc] = f2bf(silu_(acc));
}

// ---------------- K6: x_dbl = Wx[k] @ u ----------------
__global__ __launch_bounds__(256) void k_xdbl(const u16* __restrict__ xc,
    const float* __restrict__ Wx, float* __restrict__ xdbl) {
  __shared__ float wx[10 * 128];
  const int kb = blockIdx.y;
  const int k = kb >> 4;
  const int sp = blockIdx.x * 256 + threadIdx.x;
  for (int i = threadIdx.x; i < 1280; i += 256) wx[i] = Wx[(size_t)k * 1280 + i];
  __syncthreads();
  float acc[10] = {};
  const u16* up = xc + ((size_t)kb * L_ + sp) * 128;
  for (int q = 0; q < 16; ++q) {
    uint4 v = *(const uint4*)(up + q * 8);
    float e[8] = {bflo(v.x), bfhi(v.x), bflo(v.y), bfhi(v.y),
                  bflo(v.z), bfhi(v.z), bflo(v.w), bfhi(v.w)};
    #pragma unroll
    for (int r = 0; r < 10; ++r) {
      const float* wr = &wx[r * 128 + q * 8];
      #pragma unroll
      for (int j = 0; j < 8; ++j) acc[r] += wr[j] * e[j];
    }
  }
  float* o = xdbl + ((size_t)kb * L_ + sp) * 16;
  #pragma unroll
  for (int r = 0; r < 10; ++r) o[r] = acc[r];
}

// ---------------- K7: scan pass A: segment aggregates + materialize delta (bf16) ----------------
__global__ __launch_bounds__(128) void k_scan_passA(const u16* __restrict__ xc,
    const float* __restrict__ xdbl, const float* __restrict__ Wdt, const float* __restrict__ dtb,
    const float* __restrict__ Alog, float* __restrict__ segA, float* __restrict__ segB,
    u16* __restrict__ delt) {
  const int kb = blockIdx.y;
  const int k = kb >> 4;
  const int s = blockIdx.x;
  const int dc = threadIdx.x;
  float wdt[8];
  #pragma unroll
  for (int r = 0; r < 8; ++r) wdt[r] = Wdt[((size_t)k * 128 + dc) * 8 + r];
  const float bias = dtb[k * 128 + dc];
  const float Aa = -__expf(Alog[k * 128 + dc]);
  int sp0, step;
  seg_affine(k, s, sp0, step);
  const u16* up = xc + ((size_t)kb * L_ + sp0) * 128 + dc;
  u16* dp = delt + ((size_t)kb * L_ + sp0) * 128 + dc;
  const float* xr = xdbl + ((size_t)kb * L_ + sp0) * 16;
  const int ustep = step * 128, xstep = step * 16;
  float a = 1.f, bacc = 0.f;
  #pragma unroll 4
  for (int i = 0; i < TSEG_; ++i) {
    float4 q0 = *(const float4*)(xr);
    float4 q1 = *(const float4*)(xr + 4);
    float2 q2 = *(const float2*)(xr + 8);
    float u = bf2f(*up);
    float dt = bias + wdt[0] * q0.x + wdt[1] * q0.y + wdt[2] * q0.z + wdt[3] * q0.w
                    + wdt[4] * q1.x + wdt[5] * q1.y + wdt[6] * q1.z + wdt[7] * q1.w;
    float delta = (dt > 20.f) ? dt : log1pf(__expf(dt));
    *dp = f2bf(delta);
    float dA = __expf(delta * Aa);
    float dBu = delta * u * q2.x;
    a *= dA;
    bacc = dA * bacc + dBu;
    up += ustep; dp += ustep; xr += xstep;
  }
  segA[((size_t)kb * SEG_ + s) * 128 + dc] = a;
  segB[((size_t)kb * SEG_ + s) * 128 + dc] = bacc;
}

// ---------------- K8: scan pass B ----------------
__global__ __launch_bounds__(128) void k_scan_passB(const float* __restrict__ segA,
    const float* __restrict__ segB, float* __restrict__ hpre) {
  const int kb = blockIdx.x;
  const int dc = threadIdx.x;
  float h = 0.f;
  for (int s = 0; s < SEG_; ++s) {
    size_t o = ((size_t)kb * SEG_ + s) * 128 + dc;
    hpre[o] = h;
    h = segA[o] * h + segB[o];
  }
}

// ---------------- K9: scan pass C: apply + fused onorm-LN + silu gate, t in place over xc ----------------
__global__ __launch_bounds__(128) void k_scan_passC(u16* __restrict__ xc,
    const u16* __restrict__ delt, const float* __restrict__ xdbl, const u16* __restrict__ zbuf,
    const float* __restrict__ Alog, const float* __restrict__ Dp, const float* __restrict__ hpre,
    const float* __restrict__ ow, const float* __restrict__ ob) {
  __shared__ float sm[2][4];
  const int kb = blockIdx.y;
  const int k = kb >> 4;
  const int s = blockIdx.x;
  const int dc = threadIdx.x;
  const int lane = dc & 63, wid = dc >> 6;
  const float Aa = -__expf(Alog[k * 128 + dc]);
  const float Dv = Dp[k * 128 + dc];
  const float lw = ow[k * 128 + dc], lb = ob[k * 128 + dc];
  int sp0, step;
  seg_affine(k, s, sp0, step);
  u16* up = xc + ((size_t)kb * L_ + sp0) * 128 + dc;
  const u16* dp = delt + ((size_t)kb * L_ + sp0) * 128 + dc;
  const u16* zp = zbuf + ((size_t)kb * L_ + sp0) * 128 + dc;
  const float* xr = xdbl + ((size_t)kb * L_ + sp0) * 16;
  const int ustep = step * 128, xstep = step * 16;
  float h = hpre[((size_t)kb * SEG_ + s) * 128 + dc];
  for (int i = 0; i < TSEG_; ++i) {
    float2 q2 = *(const float2*)(xr + 8);
    float u = bf2f(*up);
    float delta = bf2f(*dp);
    float g = silu_(bf2f(*zp));
    float dA = __expf(delta * Aa);
    h = dA * h + delta * u * q2.x;
    float yv = h * q2.y + Dv * u;
    float s1 = yv, s2 = yv * yv;
    #pragma unroll
    for (int o = 32; o; o >>= 1) { s1 += __shfl_xor(s1, o, 64); s2 += __shfl_xor(s2, o, 64); }
    if (lane == 0) { sm[i & 1][wid * 2] = s1; sm[i & 1][wid * 2 + 1] = s2; }
    __syncthreads();
    float S1 = sm[i & 1][0] + sm[i & 1][2];
    float S2 = sm[i & 1][1] + sm[i & 1][3];
    float mean = S1 * (1.f / 128.f);
    float rstd = rsqrtf(S2 * (1.f / 128.f) - mean * mean + 1e-5f);
    *up = f2bf(((yv - mean) * rstd * lw + lb) * g);
    up += ustep; dp += ustep; zp += ustep; xr += xstep;
  }
}

// ---------------- K11: Wout GEMM (MFMA) + (skip * xh * se) epilogue ----------------
__global__ __launch_bounds__(256) void k_gemm_wout(const u16* __restrict__ t,
    const u16* __restrict__ WoutT, const u16* __restrict__ xs, const float* __restrict__ se,
    const float* __restrict__ skip, u16* __restrict__ xm2) {
  __shared__ u16 lds[16384];
  u16* As = lds; u16* Bs = lds + 8192;
  const int k = blockIdx.z;
  const int m0 = blockIdx.y * 128;
  const int tid = threadIdx.x, l = tid & 63, w = tid >> 6;
  const int wm = w >> 1, wn = w & 1;
  const int fr = l & 15, fg = l >> 4;
  f32x4 acc[4][4];
  #pragma unroll
  for (int mi = 0; mi < 4; ++mi)
    #pragma unroll
    for (int ni = 0; ni < 4; ++ni) acc[mi][ni] = (f32x4){0.f, 0.f, 0.f, 0.f};
  const u16* Ag = t + ((size_t)k * M_ + m0) * 128;
  const u16* Bg = WoutT + (size_t)k * 16384;
  #pragma unroll
  for (int kk0 = 0; kk0 < 128; kk0 += 64) {
    stage_tile(As, Ag + kk0, 128);
    stage_tile(Bs, Bg + kk0, 128);
    __syncthreads();
    bf16x8 af[2][4], bfr[2][4];
    #pragma unroll
    for (int h = 0; h < 2; ++h)
      #pragma unroll
      for (int s = 0; s < 4; ++s) {
        af[h][s]  = lds_frag(As, wm * 64 + s * 16 + fr, h * 64 + fg * 16);
        bfr[h][s] = lds_frag(Bs, wn * 64 + s * 16 + fr, h * 64 + fg * 16);
      }
    #pragma unroll
    for (int h = 0; h < 2; ++h)
      #pragma unroll
      for (int mi = 0; mi < 4; ++mi)
        #pragma unroll
        for (int ni = 0; ni < 4; ++ni)
          acc[mi][ni] = __builtin_amdgcn_mfma_f32_16x16x32_bf16(af[h][mi], bfr[h][ni], acc[mi][ni], 0, 0, 0);
    __syncthreads();
  }
  #pragma unroll
  for (int mi = 0; mi < 4; ++mi)
    #pragma unroll
    for (int ni = 0; ni < 4; ++ni)
      #pragma unroll
      for (int j = 0; j < 4; ++j)
        lds[(wm * 64 + mi * 16 + fg * 4 + j) * 128 + wn * 64 + ni * 16 + fr] = f2bf(acc[mi][ni][j]);
  __syncthreads();
  const float sk = skip[0];
  const int b = m0 / L_;
  for (int idx = tid; idx < 128 * 16; idx += 256) {
    int row = idx >> 4, q = idx & 15;
    int m = m0 + row, c = k * 128 + q * 8;
    uint4 cv = *(const uint4*)&lds[row * 128 + q * 8];
    uint4 xv = *(const uint4*)&xs[(size_t)m * 512 + c];
    float4 s0 = *(const float4*)&se[b * 512 + c];
    float4 s1 = *(const float4*)&se[b * 512 + c + 4];
    float o[8];
    o[0] = bflo(cv.x) * sk * bflo(xv.x) * s0.x;
    o[1] = bfhi(cv.x) * sk * bfhi(xv.x) * s0.y;
    o[2] = bflo(cv.y) * sk * bflo(xv.y) * s0.z;
    o[3] = bfhi(cv.y) * sk * bfhi(xv.y) * s0.w;
    o[4] = bflo(cv.z) * sk * bflo(xv.z) * s1.x;
    o[5] = bfhi(cv.z) * sk * bfhi(xv.z) * s1.y;
    o[6] = bflo(cv.w) * sk * bflo(xv.w) * s1.z;
    o[7] = bfhi(cv.w) * sk * bfhi(xv.w) * s1.w;
    u16 ov[8];
    #pragma unroll
    for (int j = 0; j < 8; ++j) ov[j] = f2bf(o[j]);
    *(uint4*)&xm2[(size_t)m * 512 + c] = *(const uint4*)ov;
  }
}

// ---------------- K12: LN over C (rows of 512) ----------------
__global__ __launch_bounds__(256) void k_ln_rows512(const u16* __restrict__ in,
    const float* __restrict__ w, const float* __restrict__ bia, u16* __restrict__ outp) {
  const int row = blockIdx.x * 4 + (threadIdx.x >> 6);
  const int lane = threadIdx.x & 63;
  const u16* r = in + (size_t)row * C_;
  float v[8];
  float s1 = 0.f, s2 = 0.f;
  #pragma unroll
  for (int i = 0; i < 8; ++i) { v[i] = bf2f(r[lane + i * 64]); s1 += v[i]; s2 += v[i] * v[i]; }
  #pragma unroll
  for (int o = 32; o; o >>= 1) { s1 += __shfl_xor(s1, o, 64); s2 += __shfl_xor(s2, o, 64); }
  float mean = s1 * (1.f / C_);
  float rstd = rsqrtf(s2 * (1.f / C_) - mean * mean + 1e-5f);
  #pragma unroll
  for (int i = 0; i < 8; ++i) {
    int c = lane + i * 64;
    outp[(size_t)row * C_ + c] = f2bf((v[i] - mean) * rstd * w[c] + bia[c]);
  }
}

// ---------------- K13: proj GEMM (MFMA) + bias, transposed write to (B,C,H,W) ----------------
__global__ __launch_bounds__(256) void k_gemm_proj(const u16* __restrict__ xln,
    const u16* __restrict__ projwT, const float* __restrict__ projb, float* __restrict__ outp) {
  __shared__ float ldsp[8448];
  u16* As = (u16*)ldsp; u16* Bs = As + 8192;
  const int n0 = blockIdx.x * 128;
  const int m0 = blockIdx.y * 128;
  const int tid = threadIdx.x, l = tid & 63, w = tid >> 6;
  const int wm = w >> 1, wn = w & 1;
  const int fr = l & 15, fg = l >> 4;
  f32x4 acc[4][4];
  #pragma unroll
  for (int mi = 0; mi < 4; ++mi)
    #pragma unroll
    for (int ni = 0; ni < 4; ++ni) acc[mi][ni] = (f32x4){0.f, 0.f, 0.f, 0.f};
  const u16* Ag = xln + (size_t)m0 * 512;
  const u16* Bg = projwT + (size_t)n0 * 512;
  for (int kk0 = 0; kk0 < 512; kk0 += 64) {
    stage_tile(As, Ag + kk0, 512);
    stage_tile(Bs, Bg + kk0, 512);
    __syncthreads();
    bf16x8 af[2][4], bfr[2][4];
    #pragma unroll
    for (int h = 0; h < 2; ++h)
      #pragma unroll
      for (int s = 0; s < 4; ++s) {
        af[h][s]  = lds_frag(As, wm * 64 + s * 16 + fr, h * 64 + fg * 16);
        bfr[h][s] = lds_frag(Bs, wn * 64 + s * 16 + fr, h * 64 + fg * 16);
      }
    #pragma unroll
    for (int h = 0; h < 2; ++h)
      #pragma unroll
      for (int mi = 0; mi < 4; ++mi)
        #pragma unroll
        for (int ni = 0; ni < 4; ++ni)
          acc[mi][ni] = __builtin_amdgcn_mfma_f32_16x16x32_bf16(af[h][mi], bfr[h][ni], acc[mi][ni], 0, 0, 0);
    __syncthreads();
  }
  const int b = m0 / L_, sp0 = m0 % L_;
  #pragma unroll
  for (int half = 0; half < 2; ++half) {
    if (wn == half) {
      #pragma unroll
      for (int ni = 0; ni < 4; ++ni) {
        int nl = ni * 16 + fr;
        float bias = projb[n0 + half * 64 + nl];
        #pragma unroll
        for (int mi = 0; mi < 4; ++mi)
          #pragma unroll
          for (int j = 0; j < 4; ++j)
            ldsp[nl * 132 + wm * 64 + mi * 16 + fg * 4 + j] = acc[mi][ni][j] + bias;
      }
    }
    __syncthreads();
    for (int idx = tid; idx < 64 * 32; idx += 256) {
      int n = idx >> 5, mq = idx & 31;
      float4 v = *(const float4*)&ldsp[n * 132 + mq * 4];
      *(float4*)&outp[((size_t)b * 512 + n0 + half * 64 + n) * L_ + sp0 + mq * 4] = v;
    }
    __syncthreads();
  }
}

extern "C" void kernel_launch(void* const* d_in, const int* in_sizes, int n_in,
                              void* d_out, int out_size, void* d_ws, size_t ws_size,
                              hipStream_t stream) {
  const float* x     = (const float*)d_in[0];
  const float* nw    = (const float*)d_in[1];
  const float* nb    = (const float*)d_in[2];
  const float* fc1w  = (const float*)d_in[3];
  const float* fc1b  = (const float*)d_in[4];
  const float* fc2w  = (const float*)d_in[5];
  const float* fc2b  = (const float*)d_in[6];
  const float* Win   = (const float*)d_in[7];
  const float* convw = (const float*)d_in[8];
  const float* convb = (const float*)d_in[9];
  const float* Wx    = (const float*)d_in[10];
  const float* Wdt   = (const float*)d_in[11];
  const float* dtb   = (const float*)d_in[12];
  const float* Alog  = (const float*)d_in[13];
  const float* Dp    = (const float*)d_in[14];
  const float* onw   = (const float*)d_in[15];
  const float* onb   = (const float*)d_in[16];
  const float* Wout  = (const float*)d_in[17];
  const float* projw = (const float*)d_in[18];
  const float* projb = (const float*)d_in[19];
  const float* skip  = (const float*)d_in[20];
  float* outp = (float*)d_out;

  const size_t BIGE = (size_t)4 * B_ * L_ * 128;   // 18,874,368 elements
  char* p = (char*)d_ws;
  auto carve = [&](size_t bytes) { char* r = p; p += (bytes + 255) & ~(size_t)255; return r; };
  u16*   xs     = (u16*)  carve(BIGE * 2);          // (B,L,C) bf16
  u16*   big1   = (u16*)  carve(BIGE * 2);          // xin -> delta -> xln
  u16*   big2   = (u16*)  carve(BIGE * 2);          // zbuf -> xm2
  u16*   big3   = (u16*)  carve(BIGE * 2);          // xc -> t (in place)
  float* xdbl   = (float*)carve((size_t)2359296 * 4);
  float* segA   = (float*)carve((size_t)393216 * 4);
  float* segB   = (float*)carve((size_t)393216 * 4);
  float* hpre   = (float*)carve((size_t)393216 * 4);
  float* zpart  = (float*)carve((size_t)147456 * 4);
  float* z      = (float*)carve((size_t)8192 * 4);
  float* se     = (float*)carve((size_t)8192 * 4);
  u16*   WinT   = (u16*)  carve((size_t)131072 * 2);
  u16*   WoutT  = (u16*)  carve((size_t)65536 * 2);
  u16*   projwT = (u16*)  carve((size_t)262144 * 2);

  k_prep<<<1792, 256, 0, stream>>>(Win, Wout, projw, WinT, WoutT, projwT);
  k_ln_in<<<dim3(L_ / 16, B_), 256, 0, stream>>>(x, nw, nb, xs);
  k_colsum_part<<<dim3(2, B_, 18), 256, 0, stream>>>(xs, zpart);
  k_colsum_fin<<<dim3(2, B_), 256, 0, stream>>>(zpart, z);
  k_se<<<B_, 256, 0, stream>>>(z, fc1w, fc1b, fc2w, fc2b, se);
  k_gemm_xz<<<dim3(2, M_ / 128, 4), 256, 0, stream>>>(xs, WinT, big1, big2);
  k_dwconv<<<dim3(L_ / 2, 64), 256, 0, stream>>>(big1, convw, convb, big3);
  k_xdbl<<<dim3(L_ / 256, 64), 256, 0, stream>>>(big3, Wx, xdbl);
  k_scan_passA<<<dim3(SEG_, 64), 128, 0, stream>>>(big3, xdbl, Wdt, dtb, Alog, segA, segB, big1);
  k_scan_passB<<<64, 128, 0, stream>>>(segA, segB, hpre);
  k_scan_passC<<<dim3(SEG_, 64), 128, 0, stream>>>(big3, big1, xdbl, big2, Alog, Dp, hpre, onw, onb);
  k_gemm_wout<<<dim3(1, M_ / 128, 4), 256, 0, stream>>>(big3, WoutT, xs, se, skip, big2);
  k_ln_rows512<<<M_ / 4, 256, 0, stream>>>(big2, nw, nb, big1);
  k_gemm_proj<<<dim3(4, M_ / 128), 256, 0, stream>>>(big1, projwT, projb, outp);
}

// Round 5
// 378.208 us; speedup vs baseline: 2.5093x; 1.2090x over previous
//
#include <hip/hip_runtime.h>
#include <math.h>

#define DEV static __device__ __forceinline__

typedef unsigned int  u32;
typedef unsigned short u16;

using bf16x8 = __attribute__((ext_vector_type(8))) __bf16;
using f32x4  = __attribute__((ext_vector_type(4))) float;

static constexpr int B_ = 16;
static constexpr int C_ = 512;
static constexpr int H_ = 48;
static constexpr int W_ = 48;
static constexpr int L_ = 2304;      // H*W
static constexpr int M_ = B_ * L_;   // 36864
static constexpr int SEG_ = 48;      // scan segments (2304 = 48*48)
static constexpr int TSEG_ = 48;

DEV float silu_(float v) { return v / (1.f + __expf(-v)); }
DEV float bflo(u32 p) { return __uint_as_float(p << 16); }
DEV float bfhi(u32 p) { return __uint_as_float(p & 0xffff0000u); }
DEV float bf2f(u16 v) { return __uint_as_float(((u32)v) << 16); }
DEV u16 f2bf(float f) { u32 u = __float_as_uint(f); u32 r = u + 0x7fffu + ((u >> 16) & 1u); return (u16)(r >> 16); }

// direction k, segment s (TSEG=48): sp = sp0 + step*i, i in [0,48)
DEV void seg_affine(int k, int s, int& sp0, int& step) {
  if (k == 0)      { sp0 = 48 * s;        step = 1;   }
  else if (k == 1) { sp0 = 2303 - 48 * s; step = -1;  }
  else if (k == 2) { sp0 = s;             step = 48;  }
  else             { sp0 = 2303 - s;      step = -48; }
}

// ================= MFMA GEMM helpers (128x128 tile, BK=64, 4 waves) =================
DEV void stage_tile(u16* Ls, const u16* __restrict__ g, int ld) {
  const int tid = threadIdx.x;
  #pragma unroll
  for (int i = 0; i < 4; ++i) {
    int c = i * 256 + tid;
    int row = c >> 3, slot = c & 7;
    uint4 v = *(const uint4*)(g + (size_t)row * ld + slot * 8);
    int b = row * 128 + ((slot * 16) ^ ((row & 7) << 4));
    *(uint4*)((char*)Ls + b) = v;
  }
}

DEV bf16x8 lds_frag(const u16* Ls, int row, int kbyte) {
  int b = row * 128 + (kbyte ^ ((row & 7) << 4));
  return *(const bf16x8*)((const char*)Ls + b);
}

// ---------------- K0: weight prep: transpose + bf16 convert ----------------
__global__ __launch_bounds__(256) void k_prep(const float* __restrict__ Win,
    const float* __restrict__ Wout, const float* __restrict__ projw,
    u16* __restrict__ WinT, u16* __restrict__ WoutT, u16* __restrict__ projwT) {
  int id = blockIdx.x * 256 + threadIdx.x;
  if (id < 131072) {
    int k = id >> 15, rem = id & 32767;
    int r = rem >> 8, n = rem & 255;
    WinT[(k << 15) + n * 128 + r] = f2bf(Win[id]);
  } else if (id < 196608) {
    int t = id - 131072;
    int k = t >> 14, rem = t & 16383;
    int r = rem >> 7, n = rem & 127;
    WoutT[(k << 14) + n * 128 + r] = f2bf(Wout[t]);
  } else {
    int t = id - 196608;
    int r = t >> 9, n = t & 511;
    projwT[n * 512 + r] = f2bf(projw[t]);
  }
}

// ---------------- K1: layernorm over C of x transposed to (B,L,C), bf16 out ----------------
__global__ __launch_bounds__(256) void k_ln_in(const float* __restrict__ x,
    const float* __restrict__ w, const float* __restrict__ bia, u16* __restrict__ xs) {
  __shared__ float tile[16 * 513];
  __shared__ float smean[16], srstd[16];
  const int b = blockIdx.y;
  const int l0 = blockIdx.x * 16;
  const int tid = threadIdx.x;
  const float* xb = x + (size_t)b * C_ * L_;
  for (int idx = tid; idx < C_ * 16; idx += 256) {
    int c = idx >> 4, lt = idx & 15;
    tile[lt * 513 + c] = xb[(size_t)c * L_ + l0 + lt];
  }
  __syncthreads();
  {
    const int j = tid & 15, g = tid >> 4;
    float s1 = 0.f, s2 = 0.f;
    #pragma unroll
    for (int i = 0; i < 32; ++i) {
      float v = tile[g * 513 + j + i * 16];
      s1 += v; s2 += v * v;
    }
    #pragma unroll
    for (int o = 8; o; o >>= 1) { s1 += __shfl_xor(s1, o, 16); s2 += __shfl_xor(s2, o, 16); }
    if (j == 0) {
      float mean = s1 * (1.f / C_);
      float var = s2 * (1.f / C_) - mean * mean;
      smean[g] = mean;
      srstd[g] = rsqrtf(var + 1e-5f);
    }
  }
  __syncthreads();
  for (int idx = tid; idx < 16 * C_; idx += 256) {
    int lt = idx >> 9, c = idx & 511;
    float v = (tile[lt * 513 + c] - smean[lt]) * srstd[lt] * w[c] + bia[c];
    xs[((size_t)b * L_ + l0 + lt) * C_ + c] = f2bf(v);
  }
}

// ---------------- K2: column means for SE ----------------
__global__ __launch_bounds__(256) void k_colsum_part(const u16* __restrict__ xs, float* __restrict__ zpart) {
  const int c = blockIdx.x * 256 + threadIdx.x;
  const int b = blockIdx.y;
  const int s = blockIdx.z;
  float acc = 0.f;
  const u16* p = xs + ((size_t)b * L_ + s * 128) * C_ + c;
  for (int l = 0; l < 128; ++l) acc += bf2f(p[(size_t)l * C_]);
  zpart[((size_t)b * 18 + s) * C_ + c] = acc;
}

__global__ __launch_bounds__(256) void k_colsum_fin(const float* __restrict__ zpart, float* __restrict__ z) {
  const int c = blockIdx.x * 256 + threadIdx.x;
  const int b = blockIdx.y;
  float acc = 0.f;
  for (int s = 0; s < 18; ++s) acc += zpart[((size_t)b * 18 + s) * C_ + c];
  z[b * C_ + c] = acc * (1.f / L_);
}

// ---------------- K3: SE MLP ----------------
__global__ __launch_bounds__(256) void k_se(const float* __restrict__ z,
    const float* __restrict__ fc1w, const float* __restrict__ fc1b,
    const float* __restrict__ fc2w, const float* __restrict__ fc2b, float* __restrict__ se) {
  __shared__ float zs[512];
  __shared__ float hs[32];
  const int b = blockIdx.x, tid = threadIdx.x;
  zs[tid] = z[b * C_ + tid];
  zs[tid + 256] = z[b * C_ + tid + 256];
  __syncthreads();
  if (tid < 32) {
    float a = fc1b[tid];
    for (int c = 0; c < 512; ++c) a += zs[c] * fc1w[c * 32 + tid];
    hs[tid] = fmaxf(a, 0.f);
  }
  __syncthreads();
  for (int c = tid; c < 512; c += 256) {
    float a = fc2b[c];
    #pragma unroll
    for (int r = 0; r < 32; ++r) a += hs[r] * fc2w[r * 512 + c];
    se[b * C_ + c] = 1.f / (1.f + __expf(-a));
  }
}

// ---------------- K4: xz GEMM (MFMA) ----------------
__global__ __launch_bounds__(256) void k_gemm_xz(const u16* __restrict__ xs,
    const u16* __restrict__ WinT, u16* __restrict__ xin, u16* __restrict__ zbuf) {
  __shared__ u16 lds[16384];
  u16* As = lds; u16* Bs = lds + 8192;
  const int k = blockIdx.z;
  const int nb = blockIdx.x;
  const int m0 = blockIdx.y * 128;
  const int tid = threadIdx.x, l = tid & 63, w = tid >> 6;
  const int wm = w >> 1, wn = w & 1;
  const int fr = l & 15, fg = l >> 4;
  f32x4 acc[4][4];
  #pragma unroll
  for (int mi = 0; mi < 4; ++mi)
    #pragma unroll
    for (int ni = 0; ni < 4; ++ni) acc[mi][ni] = (f32x4){0.f, 0.f, 0.f, 0.f};
  const u16* Ag = xs + (size_t)m0 * 512 + k * 128;
  const u16* Bg = WinT + (size_t)k * 32768 + (size_t)nb * 16384;
  #pragma unroll
  for (int kk0 = 0; kk0 < 128; kk0 += 64) {
    stage_tile(As, Ag + kk0, 512);
    stage_tile(Bs, Bg + kk0, 128);
    __syncthreads();
    bf16x8 af[2][4], bfr[2][4];
    #pragma unroll
    for (int h = 0; h < 2; ++h)
      #pragma unroll
      for (int s = 0; s < 4; ++s) {
        af[h][s]  = lds_frag(As, wm * 64 + s * 16 + fr, h * 64 + fg * 16);
        bfr[h][s] = lds_frag(Bs, wn * 64 + s * 16 + fr, h * 64 + fg * 16);
      }
    #pragma unroll
    for (int h = 0; h < 2; ++h)
      #pragma unroll
      for (int mi = 0; mi < 4; ++mi)
        #pragma unroll
        for (int ni = 0; ni < 4; ++ni)
          acc[mi][ni] = __builtin_amdgcn_mfma_f32_16x16x32_bf16(af[h][mi], bfr[h][ni], acc[mi][ni], 0, 0, 0);
    __syncthreads();
  }
  #pragma unroll
  for (int mi = 0; mi < 4; ++mi)
    #pragma unroll
    for (int ni = 0; ni < 4; ++ni)
      #pragma unroll
      for (int j = 0; j < 4; ++j)
        lds[(wm * 64 + mi * 16 + fg * 4 + j) * 128 + wn * 64 + ni * 16 + fr] = f2bf(acc[mi][ni][j]);
  __syncthreads();
  u16* dst = (nb == 0 ? xin : zbuf) + ((size_t)k * M_ + m0) * 128;
  for (int idx = tid; idx < 128 * 16; idx += 256) {
    int row = idx >> 4, q = idx & 15;
    *(uint4*)&dst[(size_t)row * 128 + q * 8] = *(const uint4*)&lds[row * 128 + q * 8];
  }
}

// ---------------- K5: fused depthwise 3x3 conv + bias + silu + x_dbl ----------------
// block: 256 threads = 16 sp (one h row segment) x 16 channel-groups of 8
__global__ __launch_bounds__(256) void k_dwconv(const u16* __restrict__ xin,
    const float* __restrict__ cw, const float* __restrict__ cb, const float* __restrict__ Wx,
    u16* __restrict__ xc, float* __restrict__ xdbl) {
  __shared__ float taps[9][128];
  __shared__ float wxs[10][128];
  __shared__ float part[16][16][10];   // [sl][g][r]
  const int kb = blockIdx.y;
  const int k = kb >> 4;
  const int tid = threadIdx.x;
  for (int i = tid; i < 1152; i += 256) {
    int dc = i / 9, t = i - dc * 9;
    taps[t][dc] = cw[((size_t)k * 128 + dc) * 9 + t];
  }
  for (int i = tid; i < 1280; i += 256) wxs[i >> 7][i & 127] = Wx[(size_t)k * 1280 + i];
  __syncthreads();
  const int sl = tid >> 4, g = tid & 15;
  const int sp = blockIdx.x * 16 + sl;
  const int h = sp / W_, w = sp % W_;     // 16 | 48: h uniform per block
  const int dc0 = g * 8;
  float acc[8];
  {
    float4 b0 = *(const float4*)(cb + k * 128 + dc0);
    float4 b1 = *(const float4*)(cb + k * 128 + dc0 + 4);
    acc[0] = b0.x; acc[1] = b0.y; acc[2] = b0.z; acc[3] = b0.w;
    acc[4] = b1.x; acc[5] = b1.y; acc[6] = b1.z; acc[7] = b1.w;
  }
  const u16* base = xin + (size_t)kb * L_ * 128 + dc0;
  #pragma unroll
  for (int dy = -1; dy <= 1; ++dy) {
    int hh = h + dy;
    if (hh < 0 || hh >= H_) continue;
    #pragma unroll
    for (int dx = -1; dx <= 1; ++dx) {
      int ww = w + dx;
      if (ww < 0 || ww >= W_) continue;
      uint4 v = *(const uint4*)(base + (size_t)(hh * W_ + ww) * 128);
      const int t = (dy + 1) * 3 + dx + 1;
      acc[0] += taps[t][dc0 + 0] * bflo(v.x);
      acc[1] += taps[t][dc0 + 1] * bfhi(v.x);
      acc[2] += taps[t][dc0 + 2] * bflo(v.y);
      acc[3] += taps[t][dc0 + 3] * bfhi(v.y);
      acc[4] += taps[t][dc0 + 4] * bflo(v.z);
      acc[5] += taps[t][dc0 + 5] * bfhi(v.z);
      acc[6] += taps[t][dc0 + 6] * bflo(v.w);
      acc[7] += taps[t][dc0 + 7] * bfhi(v.w);
    }
  }
  float u[8];
  u16 ov[8];
  #pragma unroll
  for (int j = 0; j < 8; ++j) { u[j] = silu_(acc[j]); ov[j] = f2bf(u[j]); }
  *(uint4*)(xc + ((size_t)kb * L_ + sp) * 128 + dc0) = *(const uint4*)ov;
  #pragma unroll
  for (int r = 0; r < 10; ++r) {
    float pv = 0.f;
    #pragma unroll
    for (int j = 0; j < 8; ++j) pv += wxs[r][dc0 + j] * u[j];
    part[sl][g][r] = pv;
  }
  __syncthreads();
  if (tid < 160) {
    int sl2 = tid / 10, r = tid - sl2 * 10;
    float s = 0.f;
    #pragma unroll
    for (int g2 = 0; g2 < 16; ++g2) s += part[sl2][g2][r];
    xdbl[((size_t)kb * L_ + blockIdx.x * 16 + sl2) * 16 + r] = s;
  }
}

// ---------------- K7: scan pass A: segment aggregates + materialize delta (bf16) ----------------
__global__ __launch_bounds__(128) void k_scan_passA(const u16* __restrict__ xc,
    const float* __restrict__ xdbl, const float* __restrict__ Wdt, const float* __restrict__ dtb,
    const float* __restrict__ Alog, float* __restrict__ segA, float* __restrict__ segB,
    u16* __restrict__ delt) {
  const int kb = blockIdx.y;
  const int k = kb >> 4;
  const int s = blockIdx.x;
  const int dc = threadIdx.x;
  float wdt[8];
  #pragma unroll
  for (int r = 0; r < 8; ++r) wdt[r] = Wdt[((size_t)k * 128 + dc) * 8 + r];
  const float bias = dtb[k * 128 + dc];
  const float Aa = -__expf(Alog[k * 128 + dc]);
  int sp0, step;
  seg_affine(k, s, sp0, step);
  const u16* up = xc + ((size_t)kb * L_ + sp0) * 128 + dc;
  u16* dp = delt + ((size_t)kb * L_ + sp0) * 128 + dc;
  const float* xr = xdbl + ((size_t)kb * L_ + sp0) * 16;
  const int ustep = step * 128, xstep = step * 16;
  float a = 1.f, bacc = 0.f;
  #pragma unroll 4
  for (int i = 0; i < TSEG_; ++i) {
    float4 q0 = *(const float4*)(xr);
    float4 q1 = *(const float4*)(xr + 4);
    float2 q2 = *(const float2*)(xr + 8);
    float u = bf2f(*up);
    float dt = bias + wdt[0] * q0.x + wdt[1] * q0.y + wdt[2] * q0.z + wdt[3] * q0.w
                    + wdt[4] * q1.x + wdt[5] * q1.y + wdt[6] * q1.z + wdt[7] * q1.w;
    float delta = (dt > 20.f) ? dt : log1pf(__expf(dt));
    *dp = f2bf(delta);
    float dA = __expf(delta * Aa);
    float dBu = delta * u * q2.x;
    a *= dA;
    bacc = dA * bacc + dBu;
    up += ustep; dp += ustep; xr += xstep;
  }
  segA[((size_t)kb * SEG_ + s) * 128 + dc] = a;
  segB[((size_t)kb * SEG_ + s) * 128 + dc] = bacc;
}

// ---------------- K8: scan pass B ----------------
__global__ __launch_bounds__(128) void k_scan_passB(const float* __restrict__ segA,
    const float* __restrict__ segB, float* __restrict__ hpre) {
  const int kb = blockIdx.x;
  const int dc = threadIdx.x;
  float h = 0.f;
  for (int s = 0; s < SEG_; ++s) {
    size_t o = ((size_t)kb * SEG_ + s) * 128 + dc;
    hpre[o] = h;
    h = segA[o] * h + segB[o];
  }
}

// ---------------- K9: scan pass C: apply + fused onorm-LN + silu gate, t in place over xc ----------------
__global__ __launch_bounds__(128) void k_scan_passC(u16* __restrict__ xc,
    const u16* __restrict__ delt, const float* __restrict__ xdbl, const u16* __restrict__ zbuf,
    const float* __restrict__ Alog, const float* __restrict__ Dp, const float* __restrict__ hpre,
    const float* __restrict__ ow, const float* __restrict__ ob) {
  __shared__ float sm[2][4];
  const int kb = blockIdx.y;
  const int k = kb >> 4;
  const int s = blockIdx.x;
  const int dc = threadIdx.x;
  const int lane = dc & 63, wid = dc >> 6;
  const float Aa = -__expf(Alog[k * 128 + dc]);
  const float Dv = Dp[k * 128 + dc];
  const float lw = ow[k * 128 + dc], lb = ob[k * 128 + dc];
  int sp0, step;
  seg_affine(k, s, sp0, step);
  u16* up = xc + ((size_t)kb * L_ + sp0) * 128 + dc;
  const u16* dp = delt + ((size_t)kb * L_ + sp0) * 128 + dc;
  const u16* zp = zbuf + ((size_t)kb * L_ + sp0) * 128 + dc;
  const float* xr = xdbl + ((size_t)kb * L_ + sp0) * 16;
  const int ustep = step * 128, xstep = step * 16;
  float h = hpre[((size_t)kb * SEG_ + s) * 128 + dc];
  for (int i = 0; i < TSEG_; ++i) {
    float2 q2 = *(const float2*)(xr + 8);
    float u = bf2f(*up);
    float delta = bf2f(*dp);
    float g = silu_(bf2f(*zp));
    float dA = __expf(delta * Aa);
    h = dA * h + delta * u * q2.x;
    float yv = h * q2.y + Dv * u;
    float s1 = yv, s2 = yv * yv;
    #pragma unroll
    for (int o = 32; o; o >>= 1) { s1 += __shfl_xor(s1, o, 64); s2 += __shfl_xor(s2, o, 64); }
    if (lane == 0) { sm[i & 1][wid * 2] = s1; sm[i & 1][wid * 2 + 1] = s2; }
    __syncthreads();
    float S1 = sm[i & 1][0] + sm[i & 1][2];
    float S2 = sm[i & 1][1] + sm[i & 1][3];
    float mean = S1 * (1.f / 128.f);
    float rstd = rsqrtf(S2 * (1.f / 128.f) - mean * mean + 1e-5f);
    *up = f2bf(((yv - mean) * rstd * lw + lb) * g);
    up += ustep; dp += ustep; zp += ustep; xr += xstep;
  }
}

// ---------------- K11: Wout GEMM (MFMA) + (skip * xh * se) epilogue ----------------
__global__ __launch_bounds__(256) void k_gemm_wout(const u16* __restrict__ t,
    const u16* __restrict__ WoutT, const u16* __restrict__ xs, const float* __restrict__ se,
    const float* __restrict__ skip, u16* __restrict__ xm2) {
  __shared__ u16 lds[16384];
  u16* As = lds; u16* Bs = lds + 8192;
  const int k = blockIdx.z;
  const int m0 = blockIdx.y * 128;
  const int tid = threadIdx.x, l = tid & 63, w = tid >> 6;
  const int wm = w >> 1, wn = w & 1;
  const int fr = l & 15, fg = l >> 4;
  f32x4 acc[4][4];
  #pragma unroll
  for (int mi = 0; mi < 4; ++mi)
    #pragma unroll
    for (int ni = 0; ni < 4; ++ni) acc[mi][ni] = (f32x4){0.f, 0.f, 0.f, 0.f};
  const u16* Ag = t + ((size_t)k * M_ + m0) * 128;
  const u16* Bg = WoutT + (size_t)k * 16384;
  #pragma unroll
  for (int kk0 = 0; kk0 < 128; kk0 += 64) {
    stage_tile(As, Ag + kk0, 128);
    stage_tile(Bs, Bg + kk0, 128);
    __syncthreads();
    bf16x8 af[2][4], bfr[2][4];
    #pragma unroll
    for (int h = 0; h < 2; ++h)
      #pragma unroll
      for (int s = 0; s < 4; ++s) {
        af[h][s]  = lds_frag(As, wm * 64 + s * 16 + fr, h * 64 + fg * 16);
        bfr[h][s] = lds_frag(Bs, wn * 64 + s * 16 + fr, h * 64 + fg * 16);
      }
    #pragma unroll
    for (int h = 0; h < 2; ++h)
      #pragma unroll
      for (int mi = 0; mi < 4; ++mi)
        #pragma unroll
        for (int ni = 0; ni < 4; ++ni)
          acc[mi][ni] = __builtin_amdgcn_mfma_f32_16x16x32_bf16(af[h][mi], bfr[h][ni], acc[mi][ni], 0, 0, 0);
    __syncthreads();
  }
  #pragma unroll
  for (int mi = 0; mi < 4; ++mi)
    #pragma unroll
    for (int ni = 0; ni < 4; ++ni)
      #pragma unroll
      for (int j = 0; j < 4; ++j)
        lds[(wm * 64 + mi * 16 + fg * 4 + j) * 128 + wn * 64 + ni * 16 + fr] = f2bf(acc[mi][ni][j]);
  __syncthreads();
  const float sk = skip[0];
  const int b = m0 / L_;
  for (int idx = tid; idx < 128 * 16; idx += 256) {
    int row = idx >> 4, q = idx & 15;
    int m = m0 + row, c = k * 128 + q * 8;
    uint4 cv = *(const uint4*)&lds[row * 128 + q * 8];
    uint4 xv = *(const uint4*)&xs[(size_t)m * 512 + c];
    float4 s0 = *(const float4*)&se[b * 512 + c];
    float4 s1 = *(const float4*)&se[b * 512 + c + 4];
    float o[8];
    o[0] = bflo(cv.x) * sk * bflo(xv.x) * s0.x;
    o[1] = bfhi(cv.x) * sk * bfhi(xv.x) * s0.y;
    o[2] = bflo(cv.y) * sk * bflo(xv.y) * s0.z;
    o[3] = bfhi(cv.y) * sk * bfhi(xv.y) * s0.w;
    o[4] = bflo(cv.z) * sk * bflo(xv.z) * s1.x;
    o[5] = bfhi(cv.z) * sk * bfhi(xv.z) * s1.y;
    o[6] = bflo(cv.w) * sk * bflo(xv.w) * s1.z;
    o[7] = bfhi(cv.w) * sk * bfhi(xv.w) * s1.w;
    u16 ov[8];
    #pragma unroll
    for (int j = 0; j < 8; ++j) ov[j] = f2bf(o[j]);
    *(uint4*)&xm2[(size_t)m * 512 + c] = *(const uint4*)ov;
  }
}

// ---------------- K12: LN over C (rows of 512) ----------------
__global__ __launch_bounds__(256) void k_ln_rows512(const u16* __restrict__ in,
    const float* __restrict__ w, const float* __restrict__ bia, u16* __restrict__ outp) {
  const int row = blockIdx.x * 4 + (threadIdx.x >> 6);
  const int lane = threadIdx.x & 63;
  const u16* r = in + (size_t)row * C_;
  float v[8];
  float s1 = 0.f, s2 = 0.f;
  #pragma unroll
  for (int i = 0; i < 8; ++i) { v[i] = bf2f(r[lane + i * 64]); s1 += v[i]; s2 += v[i] * v[i]; }
  #pragma unroll
  for (int o = 32; o; o >>= 1) { s1 += __shfl_xor(s1, o, 64); s2 += __shfl_xor(s2, o, 64); }
  float mean = s1 * (1.f / C_);
  float rstd = rsqrtf(s2 * (1.f / C_) - mean * mean + 1e-5f);
  #pragma unroll
  for (int i = 0; i < 8; ++i) {
    int c = lane + i * 64;
    outp[(size_t)row * C_ + c] = f2bf((v[i] - mean) * rstd * w[c] + bia[c]);
  }
}

// ---------------- K13: proj GEMM (MFMA) + bias, transposed write to (B,C,H,W) ----------------
__global__ __launch_bounds__(256) void k_gemm_proj(const u16* __restrict__ xln,
    const u16* __restrict__ projwT, const float* __restrict__ projb, float* __restrict__ outp) {
  __shared__ float ldsp[8448];
  u16* As = (u16*)ldsp; u16* Bs = As + 8192;
  const int n0 = blockIdx.x * 128;
  const int m0 = blockIdx.y * 128;
  const int tid = threadIdx.x, l = tid & 63, w = tid >> 6;
  const int wm = w >> 1, wn = w & 1;
  const int fr = l & 15, fg = l >> 4;
  f32x4 acc[4][4];
  #pragma unroll
  for (int mi = 0; mi < 4; ++mi)
    #pragma unroll
    for (int ni = 0; ni < 4; ++ni) acc[mi][ni] = (f32x4){0.f, 0.f, 0.f, 0.f};
  const u16* Ag = xln + (size_t)m0 * 512;
  const u16* Bg = projwT + (size_t)n0 * 512;
  for (int kk0 = 0; kk0 < 512; kk0 += 64) {
    stage_tile(As, Ag + kk0, 512);
    stage_tile(Bs, Bg + kk0, 512);
    __syncthreads();
    bf16x8 af[2][4], bfr[2][4];
    #pragma unroll
    for (int h = 0; h < 2; ++h)
      #pragma unroll
      for (int s = 0; s < 4; ++s) {
        af[h][s]  = lds_frag(As, wm * 64 + s * 16 + fr, h * 64 + fg * 16);
        bfr[h][s] = lds_frag(Bs, wn * 64 + s * 16 + fr, h * 64 + fg * 16);
      }
    #pragma unroll
    for (int h = 0; h < 2; ++h)
      #pragma unroll
      for (int mi = 0; mi < 4; ++mi)
        #pragma unroll
        for (int ni = 0; ni < 4; ++ni)
          acc[mi][ni] = __builtin_amdgcn_mfma_f32_16x16x32_bf16(af[h][mi], bfr[h][ni], acc[mi][ni], 0, 0, 0);
    __syncthreads();
  }
  const int b = m0 / L_, sp0 = m0 % L_;
  #pragma unroll
  for (int half = 0; half < 2; ++half) {
    if (wn == half) {
      #pragma unroll
      for (int ni = 0; ni < 4; ++ni) {
        int nl = ni * 16 + fr;
        float bias = projb[n0 + half * 64 + nl];
        #pragma unroll
        for (int mi = 0; mi < 4; ++mi)
          #pragma unroll
          for (int j = 0; j < 4; ++j)
            ldsp[nl * 132 + wm * 64 + mi * 16 + fg * 4 + j] = acc[mi][ni][j] + bias;
      }
    }
    __syncthreads();
    for (int idx = tid; idx < 64 * 32; idx += 256) {
      int n = idx >> 5, mq = idx & 31;
      float4 v = *(const float4*)&ldsp[n * 132 + mq * 4];
      *(float4*)&outp[((size_t)b * 512 + n0 + half * 64 + n) * L_ + sp0 + mq * 4] = v;
    }
    __syncthreads();
  }
}

extern "C" void kernel_launch(void* const* d_in, const int* in_sizes, int n_in,
                              void* d_out, int out_size, void* d_ws, size_t ws_size,
                              hipStream_t stream) {
  const float* x     = (const float*)d_in[0];
  const float* nw    = (const float*)d_in[1];
  const float* nb    = (const float*)d_in[2];
  const float* fc1w  = (const float*)d_in[3];
  const float* fc1b  = (const float*)d_in[4];
  const float* fc2w  = (const float*)d_in[5];
  const float* fc2b  = (const float*)d_in[6];
  const float* Win   = (const float*)d_in[7];
  const float* convw = (const float*)d_in[8];
  const float* convb = (const float*)d_in[9];
  const float* Wx    = (const float*)d_in[10];
  const float* Wdt   = (const float*)d_in[11];
  const float* dtb   = (const float*)d_in[12];
  const float* Alog  = (const float*)d_in[13];
  const float* Dp    = (const float*)d_in[14];
  const float* onw   = (const float*)d_in[15];
  const float* onb   = (const float*)d_in[16];
  const float* Wout  = (const float*)d_in[17];
  const float* projw = (const float*)d_in[18];
  const float* projb = (const float*)d_in[19];
  const float* skip  = (const float*)d_in[20];
  float* outp = (float*)d_out;

  const size_t BIGE = (size_t)4 * B_ * L_ * 128;   // 18,874,368 elements
  char* p = (char*)d_ws;
  auto carve = [&](size_t bytes) { char* r = p; p += (bytes + 255) & ~(size_t)255; return r; };
  u16*   xs     = (u16*)  carve(BIGE * 2);          // (B,L,C) bf16
  u16*   big1   = (u16*)  carve(BIGE * 2);          // xin -> delta -> xln
  u16*   big2   = (u16*)  carve(BIGE * 2);          // zbuf -> xm2
  u16*   big3   = (u16*)  carve(BIGE * 2);          // xc -> t (in place)
  float* xdbl   = (float*)carve((size_t)2359296 * 4);
  float* segA   = (float*)carve((size_t)393216 * 4);
  float* segB   = (float*)carve((size_t)393216 * 4);
  float* hpre   = (float*)carve((size_t)393216 * 4);
  float* zpart  = (float*)carve((size_t)147456 * 4);
  float* z      = (float*)carve((size_t)8192 * 4);
  float* se     = (float*)carve((size_t)8192 * 4);
  u16*   WinT   = (u16*)  carve((size_t)131072 * 2);
  u16*   WoutT  = (u16*)  carve((size_t)65536 * 2);
  u16*   projwT = (u16*)  carve((size_t)262144 * 2);

  k_prep<<<1792, 256, 0, stream>>>(Win, Wout, projw, WinT, WoutT, projwT);
  k_ln_in<<<dim3(L_ / 16, B_), 256, 0, stream>>>(x, nw, nb, xs);
  k_colsum_part<<<dim3(2, B_, 18), 256, 0, stream>>>(xs, zpart);
  k_colsum_fin<<<dim3(2, B_), 256, 0, stream>>>(zpart, z);
  k_se<<<B_, 256, 0, stream>>>(z, fc1w, fc1b, fc2w, fc2b, se);
  k_gemm_xz<<<dim3(2, M_ / 128, 4), 256, 0, stream>>>(xs, WinT, big1, big2);
  k_dwconv<<<dim3(L_ / 16, 64), 256, 0, stream>>>(big1, convw, convb, Wx, big3, xdbl);
  k_scan_passA<<<dim3(SEG_, 64), 128, 0, stream>>>(big3, xdbl, Wdt, dtb, Alog, segA, segB, big1);
  k_scan_passB<<<64, 128, 0, stream>>>(segA, segB, hpre);
  k_scan_passC<<<dim3(SEG_, 64), 128, 0, stream>>>(big3, big1, xdbl, big2, Alog, Dp, hpre, onw, onb);
  k_gemm_wout<<<dim3(1, M_ / 128, 4), 256, 0, stream>>>(big3, WoutT, xs, se, skip, big2);
  k_ln_rows512<<<M_ / 4, 256, 0, stream>>>(big2, nw, nb, big1);
  k_gemm_proj<<<dim3(4, M_ / 128), 256, 0, stream>>>(big1, projwT, projb, outp);
}

// Round 6
// 372.608 us; speedup vs baseline: 2.5471x; 1.0150x over previous
//
#include <hip/hip_runtime.h>
#include <math.h>

#define DEV static __device__ __forceinline__

typedef unsigned int  u32;
typedef unsigned short u16;

using bf16x8 = __attribute__((ext_vector_type(8))) __bf16;
using f32x4  = __attribute__((ext_vector_type(4))) float;

static constexpr int B_ = 16;
static constexpr int C_ = 512;
static constexpr int H_ = 48;
static constexpr int W_ = 48;
static constexpr int L_ = 2304;      // H*W
static constexpr int M_ = B_ * L_;   // 36864
static constexpr int SEG_ = 48;      // scan segments (2304 = 48*48)
static constexpr int TSEG_ = 48;

DEV float silu_(float v) { return v / (1.f + __expf(-v)); }
DEV float bflo(u32 p) { return __uint_as_float(p << 16); }
DEV float bfhi(u32 p) { return __uint_as_float(p & 0xffff0000u); }
DEV float bf2f(u16 v) { return __uint_as_float(((u32)v) << 16); }
DEV u16 f2bf(float f) { u32 u = __float_as_uint(f); u32 r = u + 0x7fffu + ((u >> 16) & 1u); return (u16)(r >> 16); }

// direction k, segment s (TSEG=48): sp = sp0 + step*i, i in [0,48)
DEV void seg_affine(int k, int s, int& sp0, int& step) {
  if (k == 0)      { sp0 = 48 * s;        step = 1;   }
  else if (k == 1) { sp0 = 2303 - 48 * s; step = -1;  }
  else if (k == 2) { sp0 = s;             step = 48;  }
  else             { sp0 = 2303 - s;      step = -48; }
}

// ================= MFMA GEMM helpers (128x128 tile, BK=64, 4 waves) =================
DEV void stage_tile(u16* Ls, const u16* __restrict__ g, int ld) {
  const int tid = threadIdx.x;
  #pragma unroll
  for (int i = 0; i < 4; ++i) {
    int c = i * 256 + tid;
    int row = c >> 3, slot = c & 7;
    uint4 v = *(const uint4*)(g + (size_t)row * ld + slot * 8);
    int b = row * 128 + ((slot * 16) ^ ((row & 7) << 4));
    *(uint4*)((char*)Ls + b) = v;
  }
}

DEV bf16x8 lds_frag(const u16* Ls, int row, int kbyte) {
  int b = row * 128 + (kbyte ^ ((row & 7) << 4));
  return *(const bf16x8*)((const char*)Ls + b);
}

// ---------------- K0: weight prep: transpose + bf16 convert ----------------
__global__ __launch_bounds__(256) void k_prep(const float* __restrict__ Win,
    const float* __restrict__ Wout, const float* __restrict__ projw,
    u16* __restrict__ WinT, u16* __restrict__ WoutT, u16* __restrict__ projwT) {
  int id = blockIdx.x * 256 + threadIdx.x;
  if (id < 131072) {
    int k = id >> 15, rem = id & 32767;
    int r = rem >> 8, n = rem & 255;
    WinT[(k << 15) + n * 128 + r] = f2bf(Win[id]);
  } else if (id < 196608) {
    int t = id - 131072;
    int k = t >> 14, rem = t & 16383;
    int r = rem >> 7, n = rem & 127;
    WoutT[(k << 14) + n * 128 + r] = f2bf(Wout[t]);
  } else {
    int t = id - 196608;
    int r = t >> 9, n = t & 511;
    projwT[n * 512 + r] = f2bf(projw[t]);
  }
}

// ---------------- K1: layernorm over C of x transposed to (B,L,C), bf16 out ----------------
__global__ __launch_bounds__(256) void k_ln_in(const float* __restrict__ x,
    const float* __restrict__ w, const float* __restrict__ bia, u16* __restrict__ xs) {
  __shared__ float tile[16 * 513];
  __shared__ float smean[16], srstd[16];
  const int b = blockIdx.y;
  const int l0 = blockIdx.x * 16;
  const int tid = threadIdx.x;
  const float* xb = x + (size_t)b * C_ * L_;
  for (int idx = tid; idx < C_ * 16; idx += 256) {
    int c = idx >> 4, lt = idx & 15;
    tile[lt * 513 + c] = xb[(size_t)c * L_ + l0 + lt];
  }
  __syncthreads();
  {
    const int j = tid & 15, g = tid >> 4;
    float s1 = 0.f, s2 = 0.f;
    #pragma unroll
    for (int i = 0; i < 32; ++i) {
      float v = tile[g * 513 + j + i * 16];
      s1 += v; s2 += v * v;
    }
    #pragma unroll
    for (int o = 8; o; o >>= 1) { s1 += __shfl_xor(s1, o, 16); s2 += __shfl_xor(s2, o, 16); }
    if (j == 0) {
      float mean = s1 * (1.f / C_);
      float var = s2 * (1.f / C_) - mean * mean;
      smean[g] = mean;
      srstd[g] = rsqrtf(var + 1e-5f);
    }
  }
  __syncthreads();
  for (int idx = tid; idx < 16 * C_; idx += 256) {
    int lt = idx >> 9, c = idx & 511;
    float v = (tile[lt * 513 + c] - smean[lt]) * srstd[lt] * w[c] + bia[c];
    xs[((size_t)b * L_ + l0 + lt) * C_ + c] = f2bf(v);
  }
}

// ---------------- K2: column means for SE ----------------
__global__ __launch_bounds__(256) void k_colsum_part(const u16* __restrict__ xs, float* __restrict__ zpart) {
  const int c = blockIdx.x * 256 + threadIdx.x;
  const int b = blockIdx.y;
  const int s = blockIdx.z;
  float acc = 0.f;
  const u16* p = xs + ((size_t)b * L_ + s * 128) * C_ + c;
  for (int l = 0; l < 128; ++l) acc += bf2f(p[(size_t)l * C_]);
  zpart[((size_t)b * 18 + s) * C_ + c] = acc;
}

__global__ __launch_bounds__(256) void k_colsum_fin(const float* __restrict__ zpart, float* __restrict__ z) {
  const int c = blockIdx.x * 256 + threadIdx.x;
  const int b = blockIdx.y;
  float acc = 0.f;
  for (int s = 0; s < 18; ++s) acc += zpart[((size_t)b * 18 + s) * C_ + c];
  z[b * C_ + c] = acc * (1.f / L_);
}

// ---------------- K3: SE MLP ----------------
__global__ __launch_bounds__(256) void k_se(const float* __restrict__ z,
    const float* __restrict__ fc1w, const float* __restrict__ fc1b,
    const float* __restrict__ fc2w, const float* __restrict__ fc2b, float* __restrict__ se) {
  __shared__ float zs[512];
  __shared__ float hs[32];
  const int b = blockIdx.x, tid = threadIdx.x;
  zs[tid] = z[b * C_ + tid];
  zs[tid + 256] = z[b * C_ + tid + 256];
  __syncthreads();
  if (tid < 32) {
    float a = fc1b[tid];
    for (int c = 0; c < 512; ++c) a += zs[c] * fc1w[c * 32 + tid];
    hs[tid] = fmaxf(a, 0.f);
  }
  __syncthreads();
  for (int c = tid; c < 512; c += 256) {
    float a = fc2b[c];
    #pragma unroll
    for (int r = 0; r < 32; ++r) a += hs[r] * fc2w[r * 512 + c];
    se[b * C_ + c] = 1.f / (1.f + __expf(-a));
  }
}

// ---------------- K4: xz GEMM (MFMA) ----------------
__global__ __launch_bounds__(256) void k_gemm_xz(const u16* __restrict__ xs,
    const u16* __restrict__ WinT, u16* __restrict__ xin, u16* __restrict__ zbuf) {
  __shared__ u16 lds[16384];
  u16* As = lds; u16* Bs = lds + 8192;
  const int k = blockIdx.z;
  const int nb = blockIdx.x;
  const int m0 = blockIdx.y * 128;
  const int tid = threadIdx.x, l = tid & 63, w = tid >> 6;
  const int wm = w >> 1, wn = w & 1;
  const int fr = l & 15, fg = l >> 4;
  f32x4 acc[4][4];
  #pragma unroll
  for (int mi = 0; mi < 4; ++mi)
    #pragma unroll
    for (int ni = 0; ni < 4; ++ni) acc[mi][ni] = (f32x4){0.f, 0.f, 0.f, 0.f};
  const u16* Ag = xs + (size_t)m0 * 512 + k * 128;
  const u16* Bg = WinT + (size_t)k * 32768 + (size_t)nb * 16384;
  #pragma unroll
  for (int kk0 = 0; kk0 < 128; kk0 += 64) {
    stage_tile(As, Ag + kk0, 512);
    stage_tile(Bs, Bg + kk0, 128);
    __syncthreads();
    bf16x8 af[2][4], bfr[2][4];
    #pragma unroll
    for (int h = 0; h < 2; ++h)
      #pragma unroll
      for (int s = 0; s < 4; ++s) {
        af[h][s]  = lds_frag(As, wm * 64 + s * 16 + fr, h * 64 + fg * 16);
        bfr[h][s] = lds_frag(Bs, wn * 64 + s * 16 + fr, h * 64 + fg * 16);
      }
    #pragma unroll
    for (int h = 0; h < 2; ++h)
      #pragma unroll
      for (int mi = 0; mi < 4; ++mi)
        #pragma unroll
        for (int ni = 0; ni < 4; ++ni)
          acc[mi][ni] = __builtin_amdgcn_mfma_f32_16x16x32_bf16(af[h][mi], bfr[h][ni], acc[mi][ni], 0, 0, 0);
    __syncthreads();
  }
  #pragma unroll
  for (int mi = 0; mi < 4; ++mi)
    #pragma unroll
    for (int ni = 0; ni < 4; ++ni)
      #pragma unroll
      for (int j = 0; j < 4; ++j)
        lds[(wm * 64 + mi * 16 + fg * 4 + j) * 128 + wn * 64 + ni * 16 + fr] = f2bf(acc[mi][ni][j]);
  __syncthreads();
  u16* dst = (nb == 0 ? xin : zbuf) + ((size_t)k * M_ + m0) * 128;
  for (int idx = tid; idx < 128 * 16; idx += 256) {
    int row = idx >> 4, q = idx & 15;
    *(uint4*)&dst[(size_t)row * 128 + q * 8] = *(const uint4*)&lds[row * 128 + q * 8];
  }
}

// ---------------- K5: fused depthwise 3x3 conv + bias + silu + x_dbl ----------------
__global__ __launch_bounds__(256) void k_dwconv(const u16* __restrict__ xin,
    const float* __restrict__ cw, const float* __restrict__ cb, const float* __restrict__ Wx,
    u16* __restrict__ xc, float* __restrict__ xdbl) {
  __shared__ float taps[9][128];
  __shared__ float wxs[10][128];
  __shared__ float part[16][16][10];   // [sl][g][r]
  const int kb = blockIdx.y;
  const int k = kb >> 4;
  const int tid = threadIdx.x;
  for (int i = tid; i < 1152; i += 256) {
    int dc = i / 9, t = i - dc * 9;
    taps[t][dc] = cw[((size_t)k * 128 + dc) * 9 + t];
  }
  for (int i = tid; i < 1280; i += 256) wxs[i >> 7][i & 127] = Wx[(size_t)k * 1280 + i];
  __syncthreads();
  const int sl = tid >> 4, g = tid & 15;
  const int sp = blockIdx.x * 16 + sl;
  const int h = sp / W_, w = sp % W_;
  const int dc0 = g * 8;
  float acc[8];
  {
    float4 b0 = *(const float4*)(cb + k * 128 + dc0);
    float4 b1 = *(const float4*)(cb + k * 128 + dc0 + 4);
    acc[0] = b0.x; acc[1] = b0.y; acc[2] = b0.z; acc[3] = b0.w;
    acc[4] = b1.x; acc[5] = b1.y; acc[6] = b1.z; acc[7] = b1.w;
  }
  const u16* base = xin + (size_t)kb * L_ * 128 + dc0;
  #pragma unroll
  for (int dy = -1; dy <= 1; ++dy) {
    int hh = h + dy;
    if (hh < 0 || hh >= H_) continue;
    #pragma unroll
    for (int dx = -1; dx <= 1; ++dx) {
      int ww = w + dx;
      if (ww < 0 || ww >= W_) continue;
      uint4 v = *(const uint4*)(base + (size_t)(hh * W_ + ww) * 128);
      const int t = (dy + 1) * 3 + dx + 1;
      acc[0] += taps[t][dc0 + 0] * bflo(v.x);
      acc[1] += taps[t][dc0 + 1] * bfhi(v.x);
      acc[2] += taps[t][dc0 + 2] * bflo(v.y);
      acc[3] += taps[t][dc0 + 3] * bfhi(v.y);
      acc[4] += taps[t][dc0 + 4] * bflo(v.z);
      acc[5] += taps[t][dc0 + 5] * bfhi(v.z);
      acc[6] += taps[t][dc0 + 6] * bflo(v.w);
      acc[7] += taps[t][dc0 + 7] * bfhi(v.w);
    }
  }
  float u[8];
  u16 ov[8];
  #pragma unroll
  for (int j = 0; j < 8; ++j) { u[j] = silu_(acc[j]); ov[j] = f2bf(u[j]); }
  *(uint4*)(xc + ((size_t)kb * L_ + sp) * 128 + dc0) = *(const uint4*)ov;
  #pragma unroll
  for (int r = 0; r < 10; ++r) {
    float pv = 0.f;
    #pragma unroll
    for (int j = 0; j < 8; ++j) pv += wxs[r][dc0 + j] * u[j];
    part[sl][g][r] = pv;
  }
  __syncthreads();
  if (tid < 160) {
    int sl2 = tid / 10, r = tid - sl2 * 10;
    float s = 0.f;
    #pragma unroll
    for (int g2 = 0; g2 < 16; ++g2) s += part[sl2][g2][r];
    xdbl[((size_t)kb * L_ + blockIdx.x * 16 + sl2) * 16 + r] = s;
  }
}

// ---------------- K6: delta = softplus(dtb + Wdt . dt_row), bf16, fully parallel ----------------
__global__ __launch_bounds__(256) void k_delta(const float* __restrict__ xdbl,
    const float* __restrict__ Wdt, const float* __restrict__ dtb, u16* __restrict__ delt) {
  __shared__ float xdr[16][8];
  const int kb = blockIdx.y;
  const int k = kb >> 4;
  const int tid = threadIdx.x;
  if (tid < 128) {
    int sl = tid >> 3, r = tid & 7;
    xdr[sl][r] = xdbl[((size_t)kb * L_ + blockIdx.x * 16 + sl) * 16 + r];
  }
  __syncthreads();
  const int sl = tid >> 4, g = tid & 15;
  const int sp = blockIdx.x * 16 + sl;
  const int dc0 = g * 8;
  float row[8];
  #pragma unroll
  for (int r = 0; r < 8; ++r) row[r] = xdr[sl][r];
  float4 db0 = *(const float4*)(dtb + k * 128 + dc0);
  float4 db1 = *(const float4*)(dtb + k * 128 + dc0 + 4);
  float db[8] = {db0.x, db0.y, db0.z, db0.w, db1.x, db1.y, db1.z, db1.w};
  u16 ov[8];
  #pragma unroll
  for (int j = 0; j < 8; ++j) {
    const float4* wr = (const float4*)(Wdt + (size_t)k * 1024 + (dc0 + j) * 8);
    float4 w0 = wr[0], w1 = wr[1];
    float dt = db[j] + w0.x * row[0] + w0.y * row[1] + w0.z * row[2] + w0.w * row[3]
                     + w1.x * row[4] + w1.y * row[5] + w1.z * row[6] + w1.w * row[7];
    float delta = (dt > 20.f) ? dt : __logf(1.f + __expf(dt));
    ov[j] = f2bf(delta);
  }
  *(uint4*)(delt + ((size_t)kb * L_ + sp) * 128 + dc0) = *(const uint4*)ov;
}

// ---------------- K7: scan pass A: segment aggregates (light) ----------------
__global__ __launch_bounds__(256) void k_scan_passA(const u16* __restrict__ xc,
    const u16* __restrict__ delt, const float* __restrict__ xdbl,
    const float* __restrict__ Alog, float* __restrict__ segA, float* __restrict__ segB) {
  const int kb = blockIdx.y;
  const int k = kb >> 4;
  const int s = blockIdx.x * 2 + (threadIdx.x >> 7);
  const int dc = threadIdx.x & 127;
  const float Aa = -__expf(Alog[k * 128 + dc]);
  int sp0, step;
  seg_affine(k, s, sp0, step);
  const u16* up = xc + ((size_t)kb * L_ + sp0) * 128 + dc;
  const u16* dp = delt + ((size_t)kb * L_ + sp0) * 128 + dc;
  const float* xr = xdbl + ((size_t)kb * L_ + sp0) * 16 + 8;
  const int ustep = step * 128, xstep = step * 16;
  float a = 1.f, bacc = 0.f;
  #pragma unroll 4
  for (int i = 0; i < TSEG_; ++i) {
    float Bm = *xr;
    float u = bf2f(*up);
    float delta = bf2f(*dp);
    float dA = __expf(delta * Aa);
    a *= dA;
    bacc = dA * bacc + delta * u * Bm;
    up += ustep; dp += ustep; xr += xstep;
  }
  segA[((size_t)kb * SEG_ + s) * 128 + dc] = a;
  segB[((size_t)kb * SEG_ + s) * 128 + dc] = bacc;
}

// ---------------- K8: scan pass B ----------------
__global__ __launch_bounds__(128) void k_scan_passB(const float* __restrict__ segA,
    const float* __restrict__ segB, float* __restrict__ hpre) {
  const int kb = blockIdx.x;
  const int dc = threadIdx.x;
  float h = 0.f;
  for (int s = 0; s < SEG_; ++s) {
    size_t o = ((size_t)kb * SEG_ + s) * 128 + dc;
    hpre[o] = h;
    h = segA[o] * h + segB[o];
  }
}

// ---------------- K9: scan pass C: apply + fused onorm-LN + silu gate (wave-local, no barriers) ----------------
__global__ __launch_bounds__(256) void k_scan_passC(u16* __restrict__ xc,
    const u16* __restrict__ delt, const float* __restrict__ xdbl, const u16* __restrict__ zbuf,
    const float* __restrict__ Alog, const float* __restrict__ Dp, const float* __restrict__ hpre,
    const float* __restrict__ ow, const float* __restrict__ ob) {
  const int unit = blockIdx.x * 4 + (threadIdx.x >> 6);   // (kb, s) pair per wave
  const int kb = unit / SEG_;
  const int s = unit - kb * SEG_;
  const int k = kb >> 4;
  const int lane = threadIdx.x & 63;
  const float Aa0 = -__expf(Alog[k * 128 + lane]);
  const float Aa1 = -__expf(Alog[k * 128 + lane + 64]);
  const float Dv0 = Dp[k * 128 + lane],      Dv1 = Dp[k * 128 + lane + 64];
  const float lw0 = ow[k * 128 + lane],      lw1 = ow[k * 128 + lane + 64];
  const float lb0 = ob[k * 128 + lane],      lb1 = ob[k * 128 + lane + 64];
  int sp0, step;
  seg_affine(k, s, sp0, step);
  size_t base = ((size_t)kb * L_ + sp0) * 128 + lane;
  u16* up = xc + base;
  const u16* dp = delt + base;
  const u16* zp = zbuf + base;
  const float* xr = xdbl + ((size_t)kb * L_ + sp0) * 16 + 8;
  const int ustep = step * 128, xstep = step * 16;
  float h0 = hpre[((size_t)kb * SEG_ + s) * 128 + lane];
  float h1 = hpre[((size_t)kb * SEG_ + s) * 128 + lane + 64];
  for (int i = 0; i < TSEG_; ++i) {
    float Bm = xr[0], Cm = xr[1];
    float u0 = bf2f(up[0]), u1 = bf2f(up[64]);
    float d0 = bf2f(dp[0]), d1 = bf2f(dp[64]);
    float z0 = bf2f(zp[0]), z1 = bf2f(zp[64]);
    float dA0 = __expf(d0 * Aa0), dA1 = __expf(d1 * Aa1);
    h0 = dA0 * h0 + d0 * u0 * Bm;
    h1 = dA1 * h1 + d1 * u1 * Bm;
    float y0 = h0 * Cm + Dv0 * u0;
    float y1 = h1 * Cm + Dv1 * u1;
    float s1 = y0 + y1, s2 = y0 * y0 + y1 * y1;
    #pragma unroll
    for (int o = 32; o; o >>= 1) { s1 += __shfl_xor(s1, o, 64); s2 += __shfl_xor(s2, o, 64); }
    float mean = s1 * (1.f / 128.f);
    float rstd = rsqrtf(s2 * (1.f / 128.f) - mean * mean + 1e-5f);
    up[0]  = f2bf(((y0 - mean) * rstd * lw0 + lb0) * silu_(z0));
    up[64] = f2bf(((y1 - mean) * rstd * lw1 + lb1) * silu_(z1));
    up += ustep; dp += ustep; zp += ustep; xr += xstep;
  }
}

// ---------------- K11: Wout GEMM (MFMA) + (skip * xh * se) epilogue ----------------
__global__ __launch_bounds__(256) void k_gemm_wout(const u16* __restrict__ t,
    const u16* __restrict__ WoutT, const u16* __restrict__ xs, const float* __restrict__ se,
    const float* __restrict__ skip, u16* __restrict__ xm2) {
  __shared__ u16 lds[16384];
  u16* As = lds; u16* Bs = lds + 8192;
  const int k = blockIdx.z;
  const int m0 = blockIdx.y * 128;
  const int tid = threadIdx.x, l = tid & 63, w = tid >> 6;
  const int wm = w >> 1, wn = w & 1;
  const int fr = l & 15, fg = l >> 4;
  f32x4 acc[4][4];
  #pragma unroll
  for (int mi = 0; mi < 4; ++mi)
    #pragma unroll
    for (int ni = 0; ni < 4; ++ni) acc[mi][ni] = (f32x4){0.f, 0.f, 0.f, 0.f};
  const u16* Ag = t + ((size_t)k * M_ + m0) * 128;
  const u16* Bg = WoutT + (size_t)k * 16384;
  #pragma unroll
  for (int kk0 = 0; kk0 < 128; kk0 += 64) {
    stage_tile(As, Ag + kk0, 128);
    stage_tile(Bs, Bg + kk0, 128);
    __syncthreads();
    bf16x8 af[2][4], bfr[2][4];
    #pragma unroll
    for (int h = 0; h < 2; ++h)
      #pragma unroll
      for (int s = 0; s < 4; ++s) {
        af[h][s]  = lds_frag(As, wm * 64 + s * 16 + fr, h * 64 + fg * 16);
        bfr[h][s] = lds_frag(Bs, wn * 64 + s * 16 + fr, h * 64 + fg * 16);
      }
    #pragma unroll
    for (int h = 0; h < 2; ++h)
      #pragma unroll
      for (int mi = 0; mi < 4; ++mi)
        #pragma unroll
        for (int ni = 0; ni < 4; ++ni)
          acc[mi][ni] = __builtin_amdgcn_mfma_f32_16x16x32_bf16(af[h][mi], bfr[h][ni], acc[mi][ni], 0, 0, 0);
    __syncthreads();
  }
  #pragma unroll
  for (int mi = 0; mi < 4; ++mi)
    #pragma unroll
    for (int ni = 0; ni < 4; ++ni)
      #pragma unroll
      for (int j = 0; j < 4; ++j)
        lds[(wm * 64 + mi * 16 + fg * 4 + j) * 128 + wn * 64 + ni * 16 + fr] = f2bf(acc[mi][ni][j]);
  __syncthreads();
  const float sk = skip[0];
  const int b = m0 / L_;
  for (int idx = tid; idx < 128 * 16; idx += 256) {
    int row = idx >> 4, q = idx & 15;
    int m = m0 + row, c = k * 128 + q * 8;
    uint4 cv = *(const uint4*)&lds[row * 128 + q * 8];
    uint4 xv = *(const uint4*)&xs[(size_t)m * 512 + c];
    float4 s0 = *(const float4*)&se[b * 512 + c];
    float4 s1 = *(const float4*)&se[b * 512 + c + 4];
    float o[8];
    o[0] = bflo(cv.x) * sk * bflo(xv.x) * s0.x;
    o[1] = bfhi(cv.x) * sk * bfhi(xv.x) * s0.y;
    o[2] = bflo(cv.y) * sk * bflo(xv.y) * s0.z;
    o[3] = bfhi(cv.y) * sk * bfhi(xv.y) * s0.w;
    o[4] = bflo(cv.z) * sk * bflo(xv.z) * s1.x;
    o[5] = bfhi(cv.z) * sk * bfhi(xv.z) * s1.y;
    o[6] = bflo(cv.w) * sk * bflo(xv.w) * s1.z;
    o[7] = bfhi(cv.w) * sk * bfhi(xv.w) * s1.w;
    u16 ov[8];
    #pragma unroll
    for (int j = 0; j < 8; ++j) ov[j] = f2bf(o[j]);
    *(uint4*)&xm2[(size_t)m * 512 + c] = *(const uint4*)ov;
  }
}

// ---------------- K12: LN over C (rows of 512) ----------------
__global__ __launch_bounds__(256) void k_ln_rows512(const u16* __restrict__ in,
    const float* __restrict__ w, const float* __restrict__ bia, u16* __restrict__ outp) {
  const int row = blockIdx.x * 4 + (threadIdx.x >> 6);
  const int lane = threadIdx.x & 63;
  const u16* r = in + (size_t)row * C_;
  float v[8];
  float s1 = 0.f, s2 = 0.f;
  #pragma unroll
  for (int i = 0; i < 8; ++i) { v[i] = bf2f(r[lane + i * 64]); s1 += v[i]; s2 += v[i] * v[i]; }
  #pragma unroll
  for (int o = 32; o; o >>= 1) { s1 += __shfl_xor(s1, o, 64); s2 += __shfl_xor(s2, o, 64); }
  float mean = s1 * (1.f / C_);
  float rstd = rsqrtf(s2 * (1.f / C_) - mean * mean + 1e-5f);
  #pragma unroll
  for (int i = 0; i < 8; ++i) {
    int c = lane + i * 64;
    outp[(size_t)row * C_ + c] = f2bf((v[i] - mean) * rstd * w[c] + bia[c]);
  }
}

// ---------------- K13: proj GEMM (MFMA) + bias, transposed write to (B,C,H,W) ----------------
__global__ __launch_bounds__(256) void k_gemm_proj(const u16* __restrict__ xln,
    const u16* __restrict__ projwT, const float* __restrict__ projb, float* __restrict__ outp) {
  __shared__ float ldsp[8448];
  u16* As = (u16*)ldsp; u16* Bs = As + 8192;
  const int n0 = blockIdx.x * 128;
  const int m0 = blockIdx.y * 128;
  const int tid = threadIdx.x, l = tid & 63, w = tid >> 6;
  const int wm = w >> 1, wn = w & 1;
  const int fr = l & 15, fg = l >> 4;
  f32x4 acc[4][4];
  #pragma unroll
  for (int mi = 0; mi < 4; ++mi)
    #pragma unroll
    for (int ni = 0; ni < 4; ++ni) acc[mi][ni] = (f32x4){0.f, 0.f, 0.f, 0.f};
  const u16* Ag = xln + (size_t)m0 * 512;
  const u16* Bg = projwT + (size_t)n0 * 512;
  for (int kk0 = 0; kk0 < 512; kk0 += 64) {
    stage_tile(As, Ag + kk0, 512);
    stage_tile(Bs, Bg + kk0, 512);
    __syncthreads();
    bf16x8 af[2][4], bfr[2][4];
    #pragma unroll
    for (int h = 0; h < 2; ++h)
      #pragma unroll
      for (int s = 0; s < 4; ++s) {
        af[h][s]  = lds_frag(As, wm * 64 + s * 16 + fr, h * 64 + fg * 16);
        bfr[h][s] = lds_frag(Bs, wn * 64 + s * 16 + fr, h * 64 + fg * 16);
      }
    #pragma unroll
    for (int h = 0; h < 2; ++h)
      #pragma unroll
      for (int mi = 0; mi < 4; ++mi)
        #pragma unroll
        for (int ni = 0; ni < 4; ++ni)
          acc[mi][ni] = __builtin_amdgcn_mfma_f32_16x16x32_bf16(af[h][mi], bfr[h][ni], acc[mi][ni], 0, 0, 0);
    __syncthreads();
  }
  const int b = m0 / L_, sp0 = m0 % L_;
  #pragma unroll
  for (int half = 0; half < 2; ++half) {
    if (wn == half) {
      #pragma unroll
      for (int ni = 0; ni < 4; ++ni) {
        int nl = ni * 16 + fr;
        float bias = projb[n0 + half * 64 + nl];
        #pragma unroll
        for (int mi = 0; mi < 4; ++mi)
          #pragma unroll
          for (int j = 0; j < 4; ++j)
            ldsp[nl * 132 + wm * 64 + mi * 16 + fg * 4 + j] = acc[mi][ni][j] + bias;
      }
    }
    __syncthreads();
    for (int idx = tid; idx < 64 * 32; idx += 256) {
      int n = idx >> 5, mq = idx & 31;
      float4 v = *(const float4*)&ldsp[n * 132 + mq * 4];
      *(float4*)&outp[((size_t)b * 512 + n0 + half * 64 + n) * L_ + sp0 + mq * 4] = v;
    }
    __syncthreads();
  }
}

extern "C" void kernel_launch(void* const* d_in, const int* in_sizes, int n_in,
                              void* d_out, int out_size, void* d_ws, size_t ws_size,
                              hipStream_t stream) {
  const float* x     = (const float*)d_in[0];
  const float* nw    = (const float*)d_in[1];
  const float* nb    = (const float*)d_in[2];
  const float* fc1w  = (const float*)d_in[3];
  const float* fc1b  = (const float*)d_in[4];
  const float* fc2w  = (const float*)d_in[5];
  const float* fc2b  = (const float*)d_in[6];
  const float* Win   = (const float*)d_in[7];
  const float* convw = (const float*)d_in[8];
  const float* convb = (const float*)d_in[9];
  const float* Wx    = (const float*)d_in[10];
  const float* Wdt   = (const float*)d_in[11];
  const float* dtb   = (const float*)d_in[12];
  const float* Alog  = (const float*)d_in[13];
  const float* Dp    = (const float*)d_in[14];
  const float* onw   = (const float*)d_in[15];
  const float* onb   = (const float*)d_in[16];
  const float* Wout  = (const float*)d_in[17];
  const float* projw = (const float*)d_in[18];
  const float* projb = (const float*)d_in[19];
  const float* skip  = (const float*)d_in[20];
  float* outp = (float*)d_out;

  const size_t BIGE = (size_t)4 * B_ * L_ * 128;   // 18,874,368 elements
  char* p = (char*)d_ws;
  auto carve = [&](size_t bytes) { char* r = p; p += (bytes + 255) & ~(size_t)255; return r; };
  u16*   xs     = (u16*)  carve(BIGE * 2);          // (B,L,C) bf16
  u16*   big1   = (u16*)  carve(BIGE * 2);          // xin -> delta -> xln
  u16*   big2   = (u16*)  carve(BIGE * 2);          // zbuf -> xm2
  u16*   big3   = (u16*)  carve(BIGE * 2);          // xc -> t (in place)
  float* xdbl   = (float*)carve((size_t)2359296 * 4);
  float* segA   = (float*)carve((size_t)393216 * 4);
  float* segB   = (float*)carve((size_t)393216 * 4);
  float* hpre   = (float*)carve((size_t)393216 * 4);
  float* zpart  = (float*)carve((size_t)147456 * 4);
  float* z      = (float*)carve((size_t)8192 * 4);
  float* se     = (float*)carve((size_t)8192 * 4);
  u16*   WinT   = (u16*)  carve((size_t)131072 * 2);
  u16*   WoutT  = (u16*)  carve((size_t)65536 * 2);
  u16*   projwT = (u16*)  carve((size_t)262144 * 2);

  k_prep<<<1792, 256, 0, stream>>>(Win, Wout, projw, WinT, WoutT, projwT);
  k_ln_in<<<dim3(L_ / 16, B_), 256, 0, stream>>>(x, nw, nb, xs);
  k_colsum_part<<<dim3(2, B_, 18), 256, 0, stream>>>(xs, zpart);
  k_colsum_fin<<<dim3(2, B_), 256, 0, stream>>>(zpart, z);
  k_se<<<B_, 256, 0, stream>>>(z, fc1w, fc1b, fc2w, fc2b, se);
  k_gemm_xz<<<dim3(2, M_ / 128, 4), 256, 0, stream>>>(xs, WinT, big1, big2);
  k_dwconv<<<dim3(L_ / 16, 64), 256, 0, stream>>>(big1, convw, convb, Wx, big3, xdbl);
  k_delta<<<dim3(L_ / 16, 64), 256, 0, stream>>>(xdbl, Wdt, dtb, big1);
  k_scan_passA<<<dim3(SEG_ / 2, 64), 256, 0, stream>>>(big3, big1, xdbl, Alog, segA, segB);
  k_scan_passB<<<64, 128, 0, stream>>>(segA, segB, hpre);
  k_scan_passC<<<SEG_ * 64 / 4, 256, 0, stream>>>(big3, big1, xdbl, big2, Alog, Dp, hpre, onw, onb);
  k_gemm_wout<<<dim3(1, M_ / 128, 4), 256, 0, stream>>>(big3, WoutT, xs, se, skip, big2);
  k_ln_rows512<<<M_ / 4, 256, 0, stream>>>(big2, nw, nb, big1);
  k_gemm_proj<<<dim3(4, M_ / 128), 256, 0, stream>>>(big1, projwT, projb, outp);
}

// Round 7
// 323.845 us; speedup vs baseline: 2.9306x; 1.1506x over previous
//
#include <hip/hip_runtime.h>
#include <math.h>

#define DEV static __device__ __forceinline__

typedef unsigned int  u32;
typedef unsigned short u16;

using bf16x8 = __attribute__((ext_vector_type(8))) __bf16;
using f32x4  = __attribute__((ext_vector_type(4))) float;

static constexpr int B_ = 16;
static constexpr int C_ = 512;
static constexpr int H_ = 48;
static constexpr int W_ = 48;
static constexpr int L_ = 2304;      // H*W
static constexpr int M_ = B_ * L_;   // 36864
static constexpr int SEG_ = 48;      // scan segments (2304 = 48*48)
static constexpr int TSEG_ = 48;

DEV float silu_(float v) { return v / (1.f + __expf(-v)); }
DEV float bflo(u32 p) { return __uint_as_float(p << 16); }
DEV float bfhi(u32 p) { return __uint_as_float(p & 0xffff0000u); }
DEV float bf2f(u16 v) { return __uint_as_float(((u32)v) << 16); }
DEV u16 f2bf(float f) { u32 u = __float_as_uint(f); u32 r = u + 0x7fffu + ((u >> 16) & 1u); return (u16)(r >> 16); }

// direction k, segment s (TSEG=48): sp = sp0 + step*i, i in [0,48)
DEV void seg_affine(int k, int s, int& sp0, int& step) {
  if (k == 0)      { sp0 = 48 * s;        step = 1;   }
  else if (k == 1) { sp0 = 2303 - 48 * s; step = -1;  }
  else if (k == 2) { sp0 = s;             step = 48;  }
  else             { sp0 = 2303 - s;      step = -48; }
}

// ================= MFMA GEMM helpers (128x128 tile, BK=64, 4 waves) =================
DEV void stage_tile(u16* Ls, const u16* __restrict__ g, int ld) {
  const int tid = threadIdx.x;
  #pragma unroll
  for (int i = 0; i < 4; ++i) {
    int c = i * 256 + tid;
    int row = c >> 3, slot = c & 7;
    uint4 v = *(const uint4*)(g + (size_t)row * ld + slot * 8);
    int b = row * 128 + ((slot * 16) ^ ((row & 7) << 4));
    *(uint4*)((char*)Ls + b) = v;
  }
}

DEV bf16x8 lds_frag(const u16* Ls, int row, int kbyte) {
  int b = row * 128 + (kbyte ^ ((row & 7) << 4));
  return *(const bf16x8*)((const char*)Ls + b);
}

// ---------------- K0: weight prep: transpose + bf16 convert ----------------
__global__ __launch_bounds__(256) void k_prep(const float* __restrict__ Win,
    const float* __restrict__ Wout, const float* __restrict__ projw,
    u16* __restrict__ WinT, u16* __restrict__ WoutT, u16* __restrict__ projwT) {
  int id = blockIdx.x * 256 + threadIdx.x;
  if (id < 131072) {
    int k = id >> 15, rem = id & 32767;
    int r = rem >> 8, n = rem & 255;
    WinT[(k << 15) + n * 128 + r] = f2bf(Win[id]);
  } else if (id < 196608) {
    int t = id - 131072;
    int k = t >> 14, rem = t & 16383;
    int r = rem >> 7, n = rem & 127;
    WoutT[(k << 14) + n * 128 + r] = f2bf(Wout[t]);
  } else {
    int t = id - 196608;
    int r = t >> 9, n = t & 511;
    projwT[n * 512 + r] = f2bf(projw[t]);
  }
}

// ---------------- K1: layernorm over C of x transposed to (B,L,C), bf16 out ----------------
__global__ __launch_bounds__(256) void k_ln_in(const float* __restrict__ x,
    const float* __restrict__ w, const float* __restrict__ bia, u16* __restrict__ xs) {
  __shared__ float tile[16 * 513];
  __shared__ float smean[16], srstd[16];
  const int b = blockIdx.y;
  const int l0 = blockIdx.x * 16;
  const int tid = threadIdx.x;
  const float* xb = x + (size_t)b * C_ * L_;
  for (int idx = tid; idx < C_ * 16; idx += 256) {
    int c = idx >> 4, lt = idx & 15;
    tile[lt * 513 + c] = xb[(size_t)c * L_ + l0 + lt];
  }
  __syncthreads();
  {
    const int j = tid & 15, g = tid >> 4;
    float s1 = 0.f, s2 = 0.f;
    #pragma unroll
    for (int i = 0; i < 32; ++i) {
      float v = tile[g * 513 + j + i * 16];
      s1 += v; s2 += v * v;
    }
    #pragma unroll
    for (int o = 8; o; o >>= 1) { s1 += __shfl_xor(s1, o, 16); s2 += __shfl_xor(s2, o, 16); }
    if (j == 0) {
      float mean = s1 * (1.f / C_);
      float var = s2 * (1.f / C_) - mean * mean;
      smean[g] = mean;
      srstd[g] = rsqrtf(var + 1e-5f);
    }
  }
  __syncthreads();
  for (int idx = tid; idx < 16 * C_; idx += 256) {
    int lt = idx >> 9, c = idx & 511;
    float v = (tile[lt * 513 + c] - smean[lt]) * srstd[lt] * w[c] + bia[c];
    xs[((size_t)b * L_ + l0 + lt) * C_ + c] = f2bf(v);
  }
}

// ---------------- K2: column means for SE ----------------
__global__ __launch_bounds__(256) void k_colsum_part(const u16* __restrict__ xs, float* __restrict__ zpart) {
  const int c = blockIdx.x * 256 + threadIdx.x;
  const int b = blockIdx.y;
  const int s = blockIdx.z;
  float acc = 0.f;
  const u16* p = xs + ((size_t)b * L_ + s * 128) * C_ + c;
  for (int l = 0; l < 128; ++l) acc += bf2f(p[(size_t)l * C_]);
  zpart[((size_t)b * 18 + s) * C_ + c] = acc;
}

__global__ __launch_bounds__(256) void k_colsum_fin(const float* __restrict__ zpart, float* __restrict__ z) {
  const int c = blockIdx.x * 256 + threadIdx.x;
  const int b = blockIdx.y;
  float acc = 0.f;
  for (int s = 0; s < 18; ++s) acc += zpart[((size_t)b * 18 + s) * C_ + c];
  z[b * C_ + c] = acc * (1.f / L_);
}

// ---------------- K3: SE MLP ----------------
__global__ __launch_bounds__(256) void k_se(const float* __restrict__ z,
    const float* __restrict__ fc1w, const float* __restrict__ fc1b,
    const float* __restrict__ fc2w, const float* __restrict__ fc2b, float* __restrict__ se) {
  __shared__ float zs[512];
  __shared__ float hs[32];
  const int b = blockIdx.x, tid = threadIdx.x;
  zs[tid] = z[b * C_ + tid];
  zs[tid + 256] = z[b * C_ + tid + 256];
  __syncthreads();
  if (tid < 32) {
    float a = fc1b[tid];
    for (int c = 0; c < 512; ++c) a += zs[c] * fc1w[c * 32 + tid];
    hs[tid] = fmaxf(a, 0.f);
  }
  __syncthreads();
  for (int c = tid; c < 512; c += 256) {
    float a = fc2b[c];
    #pragma unroll
    for (int r = 0; r < 32; ++r) a += hs[r] * fc2w[r * 512 + c];
    se[b * C_ + c] = 1.f / (1.f + __expf(-a));
  }
}

// ---------------- K4: xz GEMM (MFMA) ----------------
__global__ __launch_bounds__(256) void k_gemm_xz(const u16* __restrict__ xs,
    const u16* __restrict__ WinT, u16* __restrict__ xin, u16* __restrict__ zbuf) {
  __shared__ u16 lds[16384];
  u16* As = lds; u16* Bs = lds + 8192;
  const int k = blockIdx.z;
  const int nb = blockIdx.x;
  const int m0 = blockIdx.y * 128;
  const int tid = threadIdx.x, l = tid & 63, w = tid >> 6;
  const int wm = w >> 1, wn = w & 1;
  const int fr = l & 15, fg = l >> 4;
  f32x4 acc[4][4];
  #pragma unroll
  for (int mi = 0; mi < 4; ++mi)
    #pragma unroll
    for (int ni = 0; ni < 4; ++ni) acc[mi][ni] = (f32x4){0.f, 0.f, 0.f, 0.f};
  const u16* Ag = xs + (size_t)m0 * 512 + k * 128;
  const u16* Bg = WinT + (size_t)k * 32768 + (size_t)nb * 16384;
  #pragma unroll
  for (int kk0 = 0; kk0 < 128; kk0 += 64) {
    stage_tile(As, Ag + kk0, 512);
    stage_tile(Bs, Bg + kk0, 128);
    __syncthreads();
    bf16x8 af[2][4], bfr[2][4];
    #pragma unroll
    for (int h = 0; h < 2; ++h)
      #pragma unroll
      for (int s = 0; s < 4; ++s) {
        af[h][s]  = lds_frag(As, wm * 64 + s * 16 + fr, h * 64 + fg * 16);
        bfr[h][s] = lds_frag(Bs, wn * 64 + s * 16 + fr, h * 64 + fg * 16);
      }
    #pragma unroll
    for (int h = 0; h < 2; ++h)
      #pragma unroll
      for (int mi = 0; mi < 4; ++mi)
        #pragma unroll
        for (int ni = 0; ni < 4; ++ni)
          acc[mi][ni] = __builtin_amdgcn_mfma_f32_16x16x32_bf16(af[h][mi], bfr[h][ni], acc[mi][ni], 0, 0, 0);
    __syncthreads();
  }
  #pragma unroll
  for (int mi = 0; mi < 4; ++mi)
    #pragma unroll
    for (int ni = 0; ni < 4; ++ni)
      #pragma unroll
      for (int j = 0; j < 4; ++j)
        lds[(wm * 64 + mi * 16 + fg * 4 + j) * 128 + wn * 64 + ni * 16 + fr] = f2bf(acc[mi][ni][j]);
  __syncthreads();
  u16* dst = (nb == 0 ? xin : zbuf) + ((size_t)k * M_ + m0) * 128;
  for (int idx = tid; idx < 128 * 16; idx += 256) {
    int row = idx >> 4, q = idx & 15;
    *(uint4*)&dst[(size_t)row * 128 + q * 8] = *(const uint4*)&lds[row * 128 + q * 8];
  }
}

// ---------------- K5: fused depthwise 3x3 conv + bias + silu + x_dbl ----------------
__global__ __launch_bounds__(256) void k_dwconv(const u16* __restrict__ xin,
    const float* __restrict__ cw, const float* __restrict__ cb, const float* __restrict__ Wx,
    u16* __restrict__ xc, float* __restrict__ xdbl) {
  __shared__ float taps[9][128];
  __shared__ float wxs[10][128];
  __shared__ float part[16][16][10];   // [sl][g][r]
  const int kb = blockIdx.y;
  const int k = kb >> 4;
  const int tid = threadIdx.x;
  for (int i = tid; i < 1152; i += 256) {
    int dc = i / 9, t = i - dc * 9;
    taps[t][dc] = cw[((size_t)k * 128 + dc) * 9 + t];
  }
  for (int i = tid; i < 1280; i += 256) wxs[i >> 7][i & 127] = Wx[(size_t)k * 1280 + i];
  __syncthreads();
  const int sl = tid >> 4, g = tid & 15;
  const int sp = blockIdx.x * 16 + sl;
  const int h = sp / W_, w = sp % W_;
  const int dc0 = g * 8;
  float acc[8];
  {
    float4 b0 = *(const float4*)(cb + k * 128 + dc0);
    float4 b1 = *(const float4*)(cb + k * 128 + dc0 + 4);
    acc[0] = b0.x; acc[1] = b0.y; acc[2] = b0.z; acc[3] = b0.w;
    acc[4] = b1.x; acc[5] = b1.y; acc[6] = b1.z; acc[7] = b1.w;
  }
  const u16* base = xin + (size_t)kb * L_ * 128 + dc0;
  #pragma unroll
  for (int dy = -1; dy <= 1; ++dy) {
    int hh = h + dy;
    if (hh < 0 || hh >= H_) continue;
    #pragma unroll
    for (int dx = -1; dx <= 1; ++dx) {
      int ww = w + dx;
      if (ww < 0 || ww >= W_) continue;
      uint4 v = *(const uint4*)(base + (size_t)(hh * W_ + ww) * 128);
      const int t = (dy + 1) * 3 + dx + 1;
      acc[0] += taps[t][dc0 + 0] * bflo(v.x);
      acc[1] += taps[t][dc0 + 1] * bfhi(v.x);
      acc[2] += taps[t][dc0 + 2] * bflo(v.y);
      acc[3] += taps[t][dc0 + 3] * bfhi(v.y);
      acc[4] += taps[t][dc0 + 4] * bflo(v.z);
      acc[5] += taps[t][dc0 + 5] * bfhi(v.z);
      acc[6] += taps[t][dc0 + 6] * bflo(v.w);
      acc[7] += taps[t][dc0 + 7] * bfhi(v.w);
    }
  }
  float u[8];
  u16 ov[8];
  #pragma unroll
  for (int j = 0; j < 8; ++j) { u[j] = silu_(acc[j]); ov[j] = f2bf(u[j]); }
  *(uint4*)(xc + ((size_t)kb * L_ + sp) * 128 + dc0) = *(const uint4*)ov;
  #pragma unroll
  for (int r = 0; r < 10; ++r) {
    float pv = 0.f;
    #pragma unroll
    for (int j = 0; j < 8; ++j) pv += wxs[r][dc0 + j] * u[j];
    part[sl][g][r] = pv;
  }
  __syncthreads();
  if (tid < 160) {
    int sl2 = tid / 10, r = tid - sl2 * 10;
    float s = 0.f;
    #pragma unroll
    for (int g2 = 0; g2 < 16; ++g2) s += part[sl2][g2][r];
    xdbl[((size_t)kb * L_ + blockIdx.x * 16 + sl2) * 16 + r] = s;
  }
}

// ---------------- K6: delta = softplus(dtb + Wdt . dt_row), bf16 ----------------
// thread -> channel mapping: dc = tid&127 (coalesced Wdt loads, hoisted), 8 sps per thread
__global__ __launch_bounds__(256) void k_delta(const float* __restrict__ xdbl,
    const float* __restrict__ Wdt, const float* __restrict__ dtb, u16* __restrict__ delt) {
  __shared__ float xrow[16][8];
  const int kb = blockIdx.y;
  const int k = kb >> 4;
  const int tid = threadIdx.x;
  const int sp0 = blockIdx.x * 16;
  if (tid < 128) {
    int sl = tid >> 3, r = tid & 7;
    xrow[sl][r] = xdbl[((size_t)kb * L_ + sp0 + sl) * 16 + r];
  }
  const int dc = tid & 127, shalf = tid >> 7;
  const float4 w0 = *(const float4*)(Wdt + (size_t)k * 1024 + dc * 8);
  const float4 w1 = *(const float4*)(Wdt + (size_t)k * 1024 + dc * 8 + 4);
  const float db = dtb[k * 128 + dc];
  __syncthreads();
  u16* dst = delt + ((size_t)kb * L_ + sp0 + shalf * 8) * 128 + dc;
  #pragma unroll
  for (int i = 0; i < 8; ++i) {
    const float* r = xrow[shalf * 8 + i];
    float dt = db + w0.x * r[0] + w0.y * r[1] + w0.z * r[2] + w0.w * r[3]
                  + w1.x * r[4] + w1.y * r[5] + w1.z * r[6] + w1.w * r[7];
    float delta = (dt > 20.f) ? dt : __logf(1.f + __expf(dt));
    dst[(size_t)i * 128] = f2bf(delta);
  }
}

// ---------------- K7: scan pass A: segment aggregates (light) ----------------
__global__ __launch_bounds__(256) void k_scan_passA(const u16* __restrict__ xc,
    const u16* __restrict__ delt, const float* __restrict__ xdbl,
    const float* __restrict__ Alog, float* __restrict__ segA, float* __restrict__ segB) {
  const int kb = blockIdx.y;
  const int k = kb >> 4;
  const int s = blockIdx.x * 2 + (threadIdx.x >> 7);
  const int dc = threadIdx.x & 127;
  const float Aa = -__expf(Alog[k * 128 + dc]);
  int sp0, step;
  seg_affine(k, s, sp0, step);
  const u16* up = xc + ((size_t)kb * L_ + sp0) * 128 + dc;
  const u16* dp = delt + ((size_t)kb * L_ + sp0) * 128 + dc;
  const float* xr = xdbl + ((size_t)kb * L_ + sp0) * 16 + 8;
  const int ustep = step * 128, xstep = step * 16;
  float a = 1.f, bacc = 0.f;
  #pragma unroll 4
  for (int i = 0; i < TSEG_; ++i) {
    float Bm = *xr;
    float u = bf2f(*up);
    float delta = bf2f(*dp);
    float dA = __expf(delta * Aa);
    a *= dA;
    bacc = dA * bacc + delta * u * Bm;
    up += ustep; dp += ustep; xr += xstep;
  }
  segA[((size_t)kb * SEG_ + s) * 128 + dc] = a;
  segB[((size_t)kb * SEG_ + s) * 128 + dc] = bacc;
}

// ---------------- K8: scan pass B ----------------
__global__ __launch_bounds__(128) void k_scan_passB(const float* __restrict__ segA,
    const float* __restrict__ segB, float* __restrict__ hpre) {
  const int kb = blockIdx.x;
  const int dc = threadIdx.x;
  float h = 0.f;
  for (int s = 0; s < SEG_; ++s) {
    size_t o = ((size_t)kb * SEG_ + s) * 128 + dc;
    hpre[o] = h;
    h = segA[o] * h + segB[o];
  }
}

// ---------------- K9: scan pass C: apply + fused onorm-LN + silu gate (wave-local, no barriers) ----------------
__global__ __launch_bounds__(256) void k_scan_passC(u16* __restrict__ xc,
    const u16* __restrict__ delt, const float* __restrict__ xdbl, const u16* __restrict__ zbuf,
    const float* __restrict__ Alog, const float* __restrict__ Dp, const float* __restrict__ hpre,
    const float* __restrict__ ow, const float* __restrict__ ob) {
  const int unit = blockIdx.x * 4 + (threadIdx.x >> 6);   // (kb, s) pair per wave
  const int kb = unit / SEG_;
  const int s = unit - kb * SEG_;
  const int k = kb >> 4;
  const int lane = threadIdx.x & 63;
  const float Aa0 = -__expf(Alog[k * 128 + lane]);
  const float Aa1 = -__expf(Alog[k * 128 + lane + 64]);
  const float Dv0 = Dp[k * 128 + lane],      Dv1 = Dp[k * 128 + lane + 64];
  const float lw0 = ow[k * 128 + lane],      lw1 = ow[k * 128 + lane + 64];
  const float lb0 = ob[k * 128 + lane],      lb1 = ob[k * 128 + lane + 64];
  int sp0, step;
  seg_affine(k, s, sp0, step);
  size_t base = ((size_t)kb * L_ + sp0) * 128 + lane;
  u16* up = xc + base;
  const u16* dp = delt + base;
  const u16* zp = zbuf + base;
  const float* xr = xdbl + ((size_t)kb * L_ + sp0) * 16 + 8;
  const int ustep = step * 128, xstep = step * 16;
  float h0 = hpre[((size_t)kb * SEG_ + s) * 128 + lane];
  float h1 = hpre[((size_t)kb * SEG_ + s) * 128 + lane + 64];
  for (int i = 0; i < TSEG_; ++i) {
    float Bm = xr[0], Cm = xr[1];
    float u0 = bf2f(up[0]), u1 = bf2f(up[64]);
    float d0 = bf2f(dp[0]), d1 = bf2f(dp[64]);
    float z0 = bf2f(zp[0]), z1 = bf2f(zp[64]);
    float dA0 = __expf(d0 * Aa0), dA1 = __expf(d1 * Aa1);
    h0 = dA0 * h0 + d0 * u0 * Bm;
    h1 = dA1 * h1 + d1 * u1 * Bm;
    float y0 = h0 * Cm + Dv0 * u0;
    float y1 = h1 * Cm + Dv1 * u1;
    float s1 = y0 + y1, s2 = y0 * y0 + y1 * y1;
    #pragma unroll
    for (int o = 32; o; o >>= 1) { s1 += __shfl_xor(s1, o, 64); s2 += __shfl_xor(s2, o, 64); }
    float mean = s1 * (1.f / 128.f);
    float rstd = rsqrtf(s2 * (1.f / 128.f) - mean * mean + 1e-5f);
    up[0]  = f2bf(((y0 - mean) * rstd * lw0 + lb0) * silu_(z0));
    up[64] = f2bf(((y1 - mean) * rstd * lw1 + lb1) * silu_(z1));
    up += ustep; dp += ustep; zp += ustep; xr += xstep;
  }
}

// ---------------- K11: Wout GEMM (MFMA) + (skip * xh * se) epilogue ----------------
__global__ __launch_bounds__(256) void k_gemm_wout(const u16* __restrict__ t,
    const u16* __restrict__ WoutT, const u16* __restrict__ xs, const float* __restrict__ se,
    const float* __restrict__ skip, u16* __restrict__ xm2) {
  __shared__ u16 lds[16384];
  u16* As = lds; u16* Bs = lds + 8192;
  const int k = blockIdx.z;
  const int m0 = blockIdx.y * 128;
  const int tid = threadIdx.x, l = tid & 63, w = tid >> 6;
  const int wm = w >> 1, wn = w & 1;
  const int fr = l & 15, fg = l >> 4;
  f32x4 acc[4][4];
  #pragma unroll
  for (int mi = 0; mi < 4; ++mi)
    #pragma unroll
    for (int ni = 0; ni < 4; ++ni) acc[mi][ni] = (f32x4){0.f, 0.f, 0.f, 0.f};
  const u16* Ag = t + ((size_t)k * M_ + m0) * 128;
  const u16* Bg = WoutT + (size_t)k * 16384;
  #pragma unroll
  for (int kk0 = 0; kk0 < 128; kk0 += 64) {
    stage_tile(As, Ag + kk0, 128);
    stage_tile(Bs, Bg + kk0, 128);
    __syncthreads();
    bf16x8 af[2][4], bfr[2][4];
    #pragma unroll
    for (int h = 0; h < 2; ++h)
      #pragma unroll
      for (int s = 0; s < 4; ++s) {
        af[h][s]  = lds_frag(As, wm * 64 + s * 16 + fr, h * 64 + fg * 16);
        bfr[h][s] = lds_frag(Bs, wn * 64 + s * 16 + fr, h * 64 + fg * 16);
      }
    #pragma unroll
    for (int h = 0; h < 2; ++h)
      #pragma unroll
      for (int mi = 0; mi < 4; ++mi)
        #pragma unroll
        for (int ni = 0; ni < 4; ++ni)
          acc[mi][ni] = __builtin_amdgcn_mfma_f32_16x16x32_bf16(af[h][mi], bfr[h][ni], acc[mi][ni], 0, 0, 0);
    __syncthreads();
  }
  #pragma unroll
  for (int mi = 0; mi < 4; ++mi)
    #pragma unroll
    for (int ni = 0; ni < 4; ++ni)
      #pragma unroll
      for (int j = 0; j < 4; ++j)
        lds[(wm * 64 + mi * 16 + fg * 4 + j) * 128 + wn * 64 + ni * 16 + fr] = f2bf(acc[mi][ni][j]);
  __syncthreads();
  const float sk = skip[0];
  const int b = m0 / L_;
  for (int idx = tid; idx < 128 * 16; idx += 256) {
    int row = idx >> 4, q = idx & 15;
    int m = m0 + row, c = k * 128 + q * 8;
    uint4 cv = *(const uint4*)&lds[row * 128 + q * 8];
    uint4 xv = *(const uint4*)&xs[(size_t)m * 512 + c];
    float4 s0 = *(const float4*)&se[b * 512 + c];
    float4 s1 = *(const float4*)&se[b * 512 + c + 4];
    float o[8];
    o[0] = bflo(cv.x) * sk * bflo(xv.x) * s0.x;
    o[1] = bfhi(cv.x) * sk * bfhi(xv.x) * s0.y;
    o[2] = bflo(cv.y) * sk * bflo(xv.y) * s0.z;
    o[3] = bfhi(cv.y) * sk * bfhi(xv.y) * s0.w;
    o[4] = bflo(cv.z) * sk * bflo(xv.z) * s1.x;
    o[5] = bfhi(cv.z) * sk * bfhi(xv.z) * s1.y;
    o[6] = bflo(cv.w) * sk * bflo(xv.w) * s1.z;
    o[7] = bfhi(cv.w) * sk * bfhi(xv.w) * s1.w;
    u16 ov[8];
    #pragma unroll
    for (int j = 0; j < 8; ++j) ov[j] = f2bf(o[j]);
    *(uint4*)&xm2[(size_t)m * 512 + c] = *(const uint4*)ov;
  }
}

// ---------------- K12: LN over C (rows of 512) ----------------
__global__ __launch_bounds__(256) void k_ln_rows512(const u16* __restrict__ in,
    const float* __restrict__ w, const float* __restrict__ bia, u16* __restrict__ outp) {
  const int row = blockIdx.x * 4 + (threadIdx.x >> 6);
  const int lane = threadIdx.x & 63;
  const u16* r = in + (size_t)row * C_;
  float v[8];
  float s1 = 0.f, s2 = 0.f;
  #pragma unroll
  for (int i = 0; i < 8; ++i) { v[i] = bf2f(r[lane + i * 64]); s1 += v[i]; s2 += v[i] * v[i]; }
  #pragma unroll
  for (int o = 32; o; o >>= 1) { s1 += __shfl_xor(s1, o, 64); s2 += __shfl_xor(s2, o, 64); }
  float mean = s1 * (1.f / C_);
  float rstd = rsqrtf(s2 * (1.f / C_) - mean * mean + 1e-5f);
  #pragma unroll
  for (int i = 0; i < 8; ++i) {
    int c = lane + i * 64;
    outp[(size_t)row * C_ + c] = f2bf((v[i] - mean) * rstd * w[c] + bia[c]);
  }
}

// ---------------- K13: proj GEMM (MFMA) + bias, transposed write to (B,C,H,W) ----------------
__global__ __launch_bounds__(256) void k_gemm_proj(const u16* __restrict__ xln,
    const u16* __restrict__ projwT, const float* __restrict__ projb, float* __restrict__ outp) {
  __shared__ float ldsp[8448];
  u16* As = (u16*)ldsp; u16* Bs = As + 8192;
  const int n0 = blockIdx.x * 128;
  const int m0 = blockIdx.y * 128;
  const int tid = threadIdx.x, l = tid & 63, w = tid >> 6;
  const int wm = w >> 1, wn = w & 1;
  const int fr = l & 15, fg = l >> 4;
  f32x4 acc[4][4];
  #pragma unroll
  for (int mi = 0; mi < 4; ++mi)
    #pragma unroll
    for (int ni = 0; ni < 4; ++ni) acc[mi][ni] = (f32x4){0.f, 0.f, 0.f, 0.f};
  const u16* Ag = xln + (size_t)m0 * 512;
  const u16* Bg = projwT + (size_t)n0 * 512;
  for (int kk0 = 0; kk0 < 512; kk0 += 64) {
    stage_tile(As, Ag + kk0, 512);
    stage_tile(Bs, Bg + kk0, 512);
    __syncthreads();
    bf16x8 af[2][4], bfr[2][4];
    #pragma unroll
    for (int h = 0; h < 2; ++h)
      #pragma unroll
      for (int s = 0; s < 4; ++s) {
        af[h][s]  = lds_frag(As, wm * 64 + s * 16 + fr, h * 64 + fg * 16);
        bfr[h][s] = lds_frag(Bs, wn * 64 + s * 16 + fr, h * 64 + fg * 16);
      }
    #pragma unroll
    for (int h = 0; h < 2; ++h)
      #pragma unroll
      for (int mi = 0; mi < 4; ++mi)
        #pragma unroll
        for (int ni = 0; ni < 4; ++ni)
          acc[mi][ni] = __builtin_amdgcn_mfma_f32_16x16x32_bf16(af[h][mi], bfr[h][ni], acc[mi][ni], 0, 0, 0);
    __syncthreads();
  }
  const int b = m0 / L_, sp0 = m0 % L_;
  #pragma unroll
  for (int half = 0; half < 2; ++half) {
    if (wn == half) {
      #pragma unroll
      for (int ni = 0; ni < 4; ++ni) {
        int nl = ni * 16 + fr;
        float bias = projb[n0 + half * 64 + nl];
        #pragma unroll
        for (int mi = 0; mi < 4; ++mi)
          #pragma unroll
          for (int j = 0; j < 4; ++j)
            ldsp[nl * 132 + wm * 64 + mi * 16 + fg * 4 + j] = acc[mi][ni][j] + bias;
      }
    }
    __syncthreads();
    for (int idx = tid; idx < 64 * 32; idx += 256) {
      int n = idx >> 5, mq = idx & 31;
      float4 v = *(const float4*)&ldsp[n * 132 + mq * 4];
      *(float4*)&outp[((size_t)b * 512 + n0 + half * 64 + n) * L_ + sp0 + mq * 4] = v;
    }
    __syncthreads();
  }
}

extern "C" void kernel_launch(void* const* d_in, const int* in_sizes, int n_in,
                              void* d_out, int out_size, void* d_ws, size_t ws_size,
                              hipStream_t stream) {
  const float* x     = (const float*)d_in[0];
  const float* nw    = (const float*)d_in[1];
  const float* nb    = (const float*)d_in[2];
  const float* fc1w  = (const float*)d_in[3];
  const float* fc1b  = (const float*)d_in[4];
  const float* fc2w  = (const float*)d_in[5];
  const float* fc2b  = (const float*)d_in[6];
  const float* Win   = (const float*)d_in[7];
  const float* convw = (const float*)d_in[8];
  const float* convb = (const float*)d_in[9];
  const float* Wx    = (const float*)d_in[10];
  const float* Wdt   = (const float*)d_in[11];
  const float* dtb   = (const float*)d_in[12];
  const float* Alog  = (const float*)d_in[13];
  const float* Dp    = (const float*)d_in[14];
  const float* onw   = (const float*)d_in[15];
  const float* onb   = (const float*)d_in[16];
  const float* Wout  = (const float*)d_in[17];
  const float* projw = (const float*)d_in[18];
  const float* projb = (const float*)d_in[19];
  const float* skip  = (const float*)d_in[20];
  float* outp = (float*)d_out;

  const size_t BIGE = (size_t)4 * B_ * L_ * 128;   // 18,874,368 elements
  char* p = (char*)d_ws;
  auto carve = [&](size_t bytes) { char* r = p; p += (bytes + 255) & ~(size_t)255; return r; };
  u16*   xs     = (u16*)  carve(BIGE * 2);          // (B,L,C) bf16
  u16*   big1   = (u16*)  carve(BIGE * 2);          // xin -> delta -> xln
  u16*   big2   = (u16*)  carve(BIGE * 2);          // zbuf -> xm2
  u16*   big3   = (u16*)  carve(BIGE * 2);          // xc -> t (in place)
  float* xdbl   = (float*)carve((size_t)2359296 * 4);
  float* segA   = (float*)carve((size_t)393216 * 4);
  float* segB   = (float*)carve((size_t)393216 * 4);
  float* hpre   = (float*)carve((size_t)393216 * 4);
  float* zpart  = (float*)carve((size_t)147456 * 4);
  float* z      = (float*)carve((size_t)8192 * 4);
  float* se     = (float*)carve((size_t)8192 * 4);
  u16*   WinT   = (u16*)  carve((size_t)131072 * 2);
  u16*   WoutT  = (u16*)  carve((size_t)65536 * 2);
  u16*   projwT = (u16*)  carve((size_t)262144 * 2);

  k_prep<<<1792, 256, 0, stream>>>(Win, Wout, projw, WinT, WoutT, projwT);
  k_ln_in<<<dim3(L_ / 16, B_), 256, 0, stream>>>(x, nw, nb, xs);
  k_colsum_part<<<dim3(2, B_, 18), 256, 0, stream>>>(xs, zpart);
  k_colsum_fin<<<dim3(2, B_), 256, 0, stream>>>(zpart, z);
  k_se<<<B_, 256, 0, stream>>>(z, fc1w, fc1b, fc2w, fc2b, se);
  k_gemm_xz<<<dim3(2, M_ / 128, 4), 256, 0, stream>>>(xs, WinT, big1, big2);
  k_dwconv<<<dim3(L_ / 16, 64), 256, 0, stream>>>(big1, convw, convb, Wx, big3, xdbl);
  k_delta<<<dim3(L_ / 16, 64), 256, 0, stream>>>(xdbl, Wdt, dtb, big1);
  k_scan_passA<<<dim3(SEG_ / 2, 64), 256, 0, stream>>>(big3, big1, xdbl, Alog, segA, segB);
  k_scan_passB<<<64, 128, 0, stream>>>(segA, segB, hpre);
  k_scan_passC<<<SEG_ * 64 / 4, 256, 0, stream>>>(big3, big1, xdbl, big2, Alog, Dp, hpre, onw, onb);
  k_gemm_wout<<<dim3(1, M_ / 128, 4), 256, 0, stream>>>(big3, WoutT, xs, se, skip, big2);
  k_ln_rows512<<<M_ / 4, 256, 0, stream>>>(big2, nw, nb, big1);
  k_gemm_proj<<<dim3(4, M_ / 128), 256, 0, stream>>>(big1, projwT, projb, outp);
}